// Round 16
// baseline (192.243 us; speedup 1.0000x reference)
//
#include <hip/hip_runtime.h>
#include <hip/hip_fp16.h>
#include <math.h>
#include <stdint.h>

#ifndef M_PI
#define M_PI 3.14159265358979323846
#endif

#define SS   129
#define LL   224
#define LL2  (LL*LL)
#define LLQ  (LL2/4)
#define LL3  (LL*LL*LL)
#define SS2  (SS*SS)
#define SS3  (SS*SS*SS)
#define CABS 0.2f
#define PAD  48

#define BLO 45.5f
#define BHI 178.5f

#define NT1  28                  // 8-tile grid per axis (Run granularity)
#define NTZ16 14                 // 16-deep rot super-tiles along z
#define ROTG  (2 * NTZ16 * 784)  // 21952 logical rot super-tiles
#define NT3  17
#define NBZ16 9                  // 16-deep back super-tiles
#define BACKG (2 * NBZ16 * 289)  // 5202 logical back blocks
#define BACKCH 17                // k_back swizzle chunk
#define BACKG_P 5304             // padded: 8*39*17
#define NTZ  28

// view-ray segmentation: 16 segs of 9
#define NSEG 16
#define SEGZ 9
#define DSEGT (NSEG * SS2)                 // 266256
// k_rot pre-work blocks, dispatched FIRST:
#define EXB1 ((DSEGT + 511) / 512)         // 521: Dseg sums + A zero
#define EXB2 4                             // Run-table build
#define EXB  (EXB1 + EXB2)
// k_mid: 2744 texp blocks (one thread per tile-colQUAD) + 1041 W blocks
#define TXB4 (2 * NTZ * LLQ / 256)         // 2744 exact
#define PREB1 ((DSEGT + 255) / 256)        // 1041
#define MIDG (TXB4 + PREB1)

// k_rot staging box: [y:16][z:18][x:22] (x stride 1, z stride 22, y stride 396)
#define RBX 22
#define RBY 16
#define RBZ 18
#define RBXZ (RBX*RBZ)           // 396
#define RBN (RBX*RBY*RBZ)        // 6336 words
#define RSXH 11                  // float2 slots per row

// k_back staging box: [y:16][z:19][x:22] (x stride 1, z stride 22, y stride 418)
#define BBX 22
#define BBY 16
#define BBZ 19
#define BBXZ (BBX*BBZ)           // 418
#define BBN (BBX*BBY*BBZ)        // 6688 words
#define BSXH 11                  // half2 slots per row

struct Mat3 { float m[9]; };
struct F3   { float x, y, z; };

__device__ __forceinline__ F3 tile_center(const Mat3& M, int ox, int oy, int oz) {
    float cbx = fmaf((float)ox + 3.5f, 2.0f / 223.0f, -1.0f);
    float cby = fmaf((float)oy + 3.5f, 2.0f / 223.0f, -1.0f);
    float cbz = fmaf((float)oz + 3.5f, 2.0f / 223.0f, -1.0f);
    F3 qc;
    qc.x = fmaf(fmaf(M.m[0], cbx, fmaf(M.m[1], cby, M.m[2] * cbz)), 111.5f, 111.5f);
    qc.y = fmaf(fmaf(M.m[3], cbx, fmaf(M.m[4], cby, M.m[5] * cbz)), 111.5f, 111.5f);
    qc.z = fmaf(fmaf(M.m[6], cbx, fmaf(M.m[7], cby, M.m[8] * cbz)), 111.5f, 111.5f);
    return qc;
}

__device__ __forceinline__ F3 tile_center16(const Mat3& M, int ox, int oy, int oz) {
    float cbx = fmaf((float)ox + 3.5f, 2.0f / 223.0f, -1.0f);
    float cby = fmaf((float)oy + 3.5f, 2.0f / 223.0f, -1.0f);
    float cbz = fmaf((float)oz + 7.5f, 2.0f / 223.0f, -1.0f);
    F3 qc;
    qc.x = fmaf(fmaf(M.m[0], cbx, fmaf(M.m[1], cby, M.m[2] * cbz)), 111.5f, 111.5f);
    qc.y = fmaf(fmaf(M.m[3], cbx, fmaf(M.m[4], cby, M.m[5] * cbz)), 111.5f, 111.5f);
    qc.z = fmaf(fmaf(M.m[6], cbx, fmaf(M.m[7], cby, M.m[8] * cbz)), 111.5f, 111.5f);
    return qc;
}

__device__ __forceinline__ bool tile_accept(F3 qc, F3 H) {
    return !(qc.x + H.x < BLO || qc.x - H.x > BHI ||
             qc.y + H.y < BLO || qc.y - H.y > BHI ||
             qc.z + H.z < BLO || qc.z - H.z > BHI);
}

__device__ __forceinline__ void qmap(const Mat3& M, int x, int y, int z,
                                     float& qx, float& qy, float& qz) {
    float bx = fmaf((float)x, 2.0f / 223.0f, -1.0f);
    float by = fmaf((float)y, 2.0f / 223.0f, -1.0f);
    float bz = fmaf((float)z, 2.0f / 223.0f, -1.0f);
    qx = fmaf(fmaf(M.m[0], bx, fmaf(M.m[1], by, M.m[2] * bz)), 111.5f, 111.5f);
    qy = fmaf(fmaf(M.m[3], bx, fmaf(M.m[4], by, M.m[5] * bz)), 111.5f, 111.5f);
    qz = fmaf(fmaf(M.m[6], bx, fmaf(M.m[7], by, M.m[8] * bz)), 111.5f, 111.5f);
}

__device__ __forceinline__ float fetch_d(const float* __restrict__ d, int z, int y, int x) {
    unsigned zz = (unsigned)(z - PAD), yy = (unsigned)(y - PAD), xx = (unsigned)(x - PAD);
    return (zz < (unsigned)SS && yy < (unsigned)SS && xx < (unsigned)SS)
        ? d[((int)zz * SS + (int)yy) * SS + (int)xx] : 0.0f;
}

__device__ __forceinline__ float fetch_T(const float* __restrict__ T, int z, int y, int x) {
    unsigned zz = (unsigned)z, yy = (unsigned)y, xx = (unsigned)x;
    return (zz < (unsigned)LL && yy < (unsigned)LL && xx < (unsigned)LL)
        ? T[((int)zz * LL + (int)yy) * LL + (int)xx] : 0.0f;
}

__device__ __forceinline__ float tri_T(const float* __restrict__ T, float qz, float qy, float qx) {
    int x0 = (int)floorf(qx), y0 = (int)floorf(qy), z0 = (int)floorf(qz);
    float wx = qx - (float)x0, wy = qy - (float)y0, wz = qz - (float)z0;
    float c000 = fetch_T(T, z0, y0, x0),     c001 = fetch_T(T, z0, y0, x0 + 1);
    float c010 = fetch_T(T, z0, y0 + 1, x0), c011 = fetch_T(T, z0, y0 + 1, x0 + 1);
    float c100 = fetch_T(T, z0 + 1, y0, x0),     c101 = fetch_T(T, z0 + 1, y0, x0 + 1);
    float c110 = fetch_T(T, z0 + 1, y0 + 1, x0), c111 = fetch_T(T, z0 + 1, y0 + 1, x0 + 1);
    float a00 = c000 + wx * (c001 - c000), a01 = c010 + wx * (c011 - c010);
    float a10 = c100 + wx * (c101 - c100), a11 = c110 + wx * (c111 - c110);
    float b0 = a00 + wy * (a01 - a00), b1 = a10 + wy * (a11 - a10);
    return b0 + wz * (b1 - b0);
}

__device__ __forceinline__ float tri_d_g(const float* __restrict__ d, float qz, float qy, float qx) {
    int x0 = (int)floorf(qx), y0 = (int)floorf(qy), z0 = (int)floorf(qz);
    float wx = qx - (float)x0, wy = qy - (float)y0, wz = qz - (float)z0;
    float c000 = fetch_d(d, z0, y0, x0),     c001 = fetch_d(d, z0, y0, x0 + 1);
    float c010 = fetch_d(d, z0, y0 + 1, x0), c011 = fetch_d(d, z0, y0 + 1, x0 + 1);
    float c100 = fetch_d(d, z0 + 1, y0, x0),     c101 = fetch_d(d, z0 + 1, y0, x0 + 1);
    float c110 = fetch_d(d, z0 + 1, y0 + 1, x0), c111 = fetch_d(d, z0 + 1, y0 + 1, x0 + 1);
    float a00 = c000 + wx * (c001 - c000), a01 = c010 + wx * (c011 - c010);
    float a10 = c100 + wx * (c101 - c100), a11 = c110 + wx * (c111 - c110);
    float b0 = a00 + wy * (a01 - a00), b1 = a10 + wy * (a11 - a10);
    return b0 + wz * (b1 - b0);
}

// trilinear from k_rot's [y:16][z:18][x:22] box (strides 396 / 22 / 1)
__device__ __forceinline__ float tri_rot(const float* __restrict__ S,
                                         float qx, float qy, float qz,
                                         int lox, int loy, int loz) {
    int x0 = (int)floorf(qx), y0 = (int)floorf(qy), z0 = (int)floorf(qz);
    float wx = qx - (float)x0, wy = qy - (float)y0, wz = qz - (float)z0;
    int i = (y0 - loy) * RBXZ + (z0 - loz) * RBX + (x0 - lox);
    float c000 = S[i],         c001 = S[i + 1];
    float cz0  = S[i + 22],    cz1  = S[i + 23];
    float cy0  = S[i + 396],   cy1  = S[i + 397];
    float cw0  = S[i + 418],   cw1  = S[i + 419];
    float a00 = c000 + wx * (c001 - c000);
    float a01 = cy0  + wx * (cy1  - cy0);
    float a10 = cz0  + wx * (cz1  - cz0);
    float a11 = cw0  + wx * (cw1  - cw0);
    float b0  = a00 + wy * (a01 - a00);
    float b1  = a10 + wy * (a11 - a10);
    return b0 + wz * (b1 - b0);
}

// trilinear from k_back's [y:16][z:19][x:22] box (strides 418 / 22 / 1)
__device__ __forceinline__ float tri_back(const float* __restrict__ S,
                                          float qx, float qy, float qz,
                                          int lox, int loy, int loz) {
    int x0 = (int)floorf(qx), y0 = (int)floorf(qy), z0 = (int)floorf(qz);
    float wx = qx - (float)x0, wy = qy - (float)y0, wz = qz - (float)z0;
    int i = (y0 - loy) * BBXZ + (z0 - loz) * BBX + (x0 - lox);
    float c000 = S[i],         c001 = S[i + 1];
    float cz0  = S[i + 22],    cz1  = S[i + 23];
    float cy0  = S[i + 418],   cy1  = S[i + 419];
    float cw0  = S[i + 440],   cw1  = S[i + 441];
    float a00 = c000 + wx * (c001 - c000);
    float a01 = cy0  + wx * (cy1  - cy0);
    float a10 = cz0  + wx * (cz1  - cz0);
    float a11 = cw0  + wx * (cw1  - cw0);
    float b0  = a00 + wy * (a01 - a00);
    float b1  = a10 + wy * (a11 - a10);
    return b0 + wz * (b1 - b0);
}

// K1: pre-work blocks FIRST [0,EXB): Dseg sums + A zero + Run table.
// Blocks [EXB, EXB+cnt8): COMPACTED accepted super-tiles via host-built List
// (sentinel -1 pads). Bijective chunked XCD swizzle on the compact index
// space: XCD x8 handles compact range [x8*cpx, (x8+1)*cpx).
// float2 staging (396 threads = 2 per (z,slot), 8 y-rows each; lox even),
// raw-sample packed T store + per-tile Ssum totals.
__global__ __launch_bounds__(512) void k_rot(const float* __restrict__ d,
        __half* __restrict__ T0, __half* __restrict__ T1,
        float* __restrict__ S0, float* __restrict__ S1,
        float* __restrict__ Dseg, float* __restrict__ A,
        unsigned short* __restrict__ Run, const int* __restrict__ List, int cpx,
        Mat3 M0, Mat3 M1, F3 H0, F3 H1, F3 G0, F3 G1) {
    int n = blockIdx.x;
    int tid = threadIdx.x;
    if (n < EXB) {                          // ---- pre-work ----
        if (n < EXB1) {
            int t = n * 512 + tid;
            if (t < 2 * SS2) A[t] = 0.0f;
            if (t >= DSEGT) return;
            int seg = t / SS2, col = t - seg * SS2;
            int zs = seg * SEGZ, ze = min(SS, zs + SEGZ);
            float run = 0.0f;
            for (int z = zs; z < ze; ++z) run += d[z * SS2 + col];
            Dseg[t] = run;
        } else {
            int id = (n - EXB1) * 512 + tid;
            if (id >= 2 * 784) return;
            int l = id / 784, r = id - l * 784;
            int ty = r / 28, tx = r - ty * 28;
            const Mat3 M = l ? M1 : M0;
            const F3  G  = l ? G1 : G0;
            int t0 = -1, t1 = -1;
            for (int tz = 0; tz < NT1; ++tz) {
                F3 qc = tile_center(M, tx * 8, ty * 8, tz * 8);
                if (tile_accept(qc, G)) { if (t0 < 0) t0 = tz; t1 = tz; }
            }
            Run[id] = (t0 < 0) ? 0xFFFFu : (unsigned short)(t0 | (t1 << 8));
        }
        return;
    }

    int nn = n - EXB;
    int x8 = nn & 7, i8 = nn >> 3;          // XCD, sequence-within-XCD
    int b = List[x8 * cpx + i8];            // compact -> logical id
    if (b < 0) return;                      // pad sentinel

    int light = b / (NTZ16 * 784);
    int r = b - light * (NTZ16 * 784);
    int tz16 = r / 784;
    int r2 = r - tz16 * 784;
    int tty = r2 / 28, ttx = r2 - tty * 28;

    const Mat3 M = light ? M1 : M0;
    const F3  H  = light ? H1 : H0;           // H16
    __half* __restrict__ T   = light ? T1 : T0;
    float* __restrict__ Ssum = light ? S1 : S0;

    int ox = ttx * 8, oy = tty * 8, oz = tz16 * 16;
    F3 qc = tile_center16(M, ox, oy, oz);

    int lox = (int)floorf(qc.x - H.x);
    lox &= ~1;                                // even for float2 staging
    int loy = (int)floorf(qc.y - H.y);
    int loz = (int)floorf(qc.z - H.z);

    __shared__ float S[RBN];
    __shared__ float Sc[1024];

    if (tid < 2 * RSXH * RBZ) {               // 396 staging threads
        int ixh = tid % RSXH;                 // float2 slot 0..10
        int izz = tid / RSXH;                 // 0..35
        int jb = 0;
        if (izz >= RBZ) { izz -= RBZ; jb = 8; }   // second half: y-rows 8..15
        bool interior = (lox >= PAD) & (lox <= PAD + SS - RBX) &
                        (loy >= PAD) & (loy <= PAD + SS - RBY) &
                        (loz >= PAD) & (loz <= PAD + SS - RBZ);
        int si = jb * RBXZ + izz * RBX + 2 * ixh;
        if (interior) {
            const float* g = d + ((size_t)(loz + izz - PAD) * SS + (loy + jb - PAD)) * SS
                               + (lox + 2 * ixh - PAD);
            #pragma unroll
            for (int j = 0; j < 8; ++j)
                *(float2*)&S[si + j * RBXZ] = *(const float2*)&g[j * SS];
        } else {
            int gx0 = lox + 2 * ixh;
            #pragma unroll
            for (int j = 0; j < 8; ++j) {
                S[si + j * RBXZ]     = fetch_d(d, loz + izz, loy + jb + j, gx0);
                S[si + j * RBXZ + 1] = fetch_d(d, loz + izz, loy + jb + j, gx0 + 1);
            }
        }
    }
    __syncthreads();

    int lx = tid & 7, ly = (tid >> 3) & 7, lz = tid >> 6;
    int col = tid & 63;
    float fx = (float)lx - 3.5f, fy = (float)ly - 3.5f, fz = (float)lz - 7.5f;
    float qx = qc.x + fmaf(M.m[0], fx, fmaf(M.m[1], fy, M.m[2] * fz));
    float qy = qc.y + fmaf(M.m[3], fx, fmaf(M.m[4], fy, M.m[5] * fz));
    float qz = qc.z + fmaf(M.m[6], fx, fmaf(M.m[7], fy, M.m[8] * fz));
    float v0 = tri_rot(S, qx, qy, qz, lox, loy, loz);
    float qx2 = qx + 8.0f * M.m[2];
    float qy2 = qy + 8.0f * M.m[5];
    float qz2 = qz + 8.0f * M.m[8];
    float v1 = tri_rot(S, qx2, qy2, qz2, lox, loy, loz);

    Sc[lz * 64 + col] = v0;
    Sc[(lz + 8) * 64 + col] = v1;
    __syncthreads();
    // merged read-only tail: waves 0-1 pack raw T rows; waves 2-3 Ssum totals
    if (tid < 128) {
        int zz = tid >> 3, ly2 = tid & 7;
        const float4* Sc4 = (const float4*)Sc;
        float4 f0 = Sc4[zz * 16 + ly2 * 2];
        float4 f1 = Sc4[zz * 16 + ly2 * 2 + 1];
        union { __half2 h[4]; float4 v; } u;
        u.h[0] = __floats2half2_rn(f0.x, f0.y);
        u.h[1] = __floats2half2_rn(f0.z, f0.w);
        u.h[2] = __floats2half2_rn(f1.x, f1.y);
        u.h[3] = __floats2half2_rn(f1.z, f1.w);
        *(float4*)&T[(size_t)(oz + zz) * LL2 + (oy + ly2) * LL + ox] = u.v;
    } else if (tid < 256) {
        int t2 = tid - 128;
        int cc = t2 & 63, h = t2 >> 6;      // h=0: lower 8-tile, h=1: upper
        float s = 0.0f;
        #pragma unroll
        for (int k = 0; k < 8; ++k) s += Sc[(h * 8 + k) * 64 + cc];
        int so = (oy + (cc >> 3)) * LL + (ox + (cc & 7));
        Ssum[(2 * tz16 + h) * LL2 + so] = s;
    }
}

// k_mid: blocks [0,TXB4): transmittance. One thread per (light, tile,
//   column-QUAD): single Run lookup, inline cross-tile suffix via float4
//   Ssum-totals loads (L2-resident, r13-proven), T via float2 (4 halves)
//   loads/stores, in-register 8-deep suffix + exp, in place.
//   blocks [TXB4,MIDG): W write (fp16) from d + Dseg.
__global__ __launch_bounds__(256) void k_mid(__half* __restrict__ T0,
        __half* __restrict__ T1, const float* __restrict__ S0,
        const float* __restrict__ S1, const unsigned short* __restrict__ Run,
        const float* __restrict__ d, const float* __restrict__ Dseg,
        __half* __restrict__ W) {
    int b = blockIdx.x;
    if (b < TXB4) {
        int id = b * 256 + threadIdx.x;        // < 2*NTZ*LLQ exactly
        int light = id / (NTZ * LLQ);
        int r = id - light * (NTZ * LLQ);
        int t = r / LLQ, cq = r - t * LLQ;
        int col = cq * 4;
        int y = col / LL, x = col - y * LL;    // x mult of 4 -> one 8-tile
        unsigned short rt = Run[light * 784 + (y >> 3) * 28 + (x >> 3)];
        if (rt == 0xFFFFu) return;
        int t0 = rt & 0xFF, t1 = rt >> 8;
        if (t < t0 || t > t1) return;
        const float* __restrict__ Ssum = light ? S1 : S0;
        float oA = 0.0f, oB = 0.0f, oC = 0.0f, oD = 0.0f;
        for (int tp = t + 1; tp <= t1; ++tp) {
            float4 s4 = *(const float4*)&Ssum[tp * LL2 + col];  // 16B aligned
            oA += s4.x; oB += s4.y; oC += s4.z; oD += s4.w;
        }
        float2* __restrict__ Tp =
            (float2*)((__half*)(light ? T1 : T0) + (size_t)(8 * t) * LL2 + col);
        float2 raw[8];
        #pragma unroll
        for (int k = 0; k < 8; ++k) raw[k] = Tp[k * LLQ];   // 4 halves each
        float4 v[8];
        #pragma unroll
        for (int k = 0; k < 8; ++k) {
            __half2 h0 = ((__half2*)&raw[k])[0];
            __half2 h1 = ((__half2*)&raw[k])[1];
            float2 f0 = __half22float2(h0), f1 = __half22float2(h1);
            v[k] = make_float4(f0.x, f0.y, f1.x, f1.y);
        }
        float sA = oA, sB = oB, sC = oC, sD = oD;
        #pragma unroll
        for (int k = 7; k >= 0; --k) {
            sA += v[k].x; sB += v[k].y; sC += v[k].z; sD += v[k].w;
            v[k].x = sA; v[k].y = sB; v[k].z = sC; v[k].w = sD;
        }
        #pragma unroll
        for (int k = 0; k < 8; ++k) {
            __half2 h0 = __floats2half2_rn(__expf(-CABS * v[k].x),
                                           __expf(-CABS * v[k].y));
            __half2 h1 = __floats2half2_rn(__expf(-CABS * v[k].z),
                                           __expf(-CABS * v[k].w));
            float2 o;
            ((__half2*)&o)[0] = h0;
            ((__half2*)&o)[1] = h1;
            Tp[k * LLQ] = o;
        }
    } else {
        int t = (b - TXB4) * 256 + threadIdx.x;
        if (t >= DSEGT) return;
        int seg = t / SS2, col = t - seg * SS2;
        int zs = seg * SEGZ, ze = min(SS, zs + SEGZ);
        float run = 0.0f;
        for (int s2 = seg + 1; s2 < NSEG; ++s2) run += Dseg[s2 * SS2 + col];
        for (int z = ze - 1; z >= zs; --z) {
            float dv = d[z * SS2 + col];
            run += dv;
            W[z * SS2 + col] = __float2half(dv * __expf(-CABS * run));
        }
    }
}

// K3: 8x8x16 super-tile; half2 staging of transmittance (418 threads = 2 per
// (z,slot), 8 y-rows each; lox even), back-rotate, *W16, reduce.
// XCD-chunked swizzle, padded grid.
template<bool BINT>
__global__ __launch_bounds__(512) void k_back(const __half* __restrict__ T0,
        const __half* __restrict__ T1, const __half* __restrict__ W,
        float* __restrict__ A0, float* __restrict__ A1,
        Mat3 M0, Mat3 M1, F3 H0, F3 H1) {
    int n = blockIdx.x;
    int x8 = n & 7, i8 = n >> 3;
    int c = i8 / BACKCH, off = i8 - c * BACKCH;
    int lb = (c * 8 + x8) * BACKCH + off;
    if (lb >= BACKG) return;

    int light = lb / (NBZ16 * 289); lb -= light * (NBZ16 * 289);
    int tz16 = lb / 289;
    int r2 = lb - tz16 * 289;
    int tty = r2 / 17, ttx = r2 - tty * 17;

    const Mat3 M = light ? M1 : M0;
    const F3  H  = light ? H1 : H0;
    const __half* __restrict__ T = light ? T1 : T0;
    float* __restrict__ A = light ? A1 : A0;

    int ox = ttx * 8, oy = tty * 8, oz = tz16 * 16;
    F3 qc = tile_center16(M, ox + PAD, oy + PAD, oz + PAD);
    int lox = (int)floorf(qc.x - H.x);
    lox &= ~1;                                // even for half2 staging
    int loy = (int)floorf(qc.y - H.y);
    int loz = (int)floorf(qc.z - H.z);

    __shared__ float S[BBN];
    __shared__ float Sc[512];
    int tid = threadIdx.x;

    if (tid < 2 * BSXH * BBZ) {               // 418 staging threads
        int ixh = tid % BSXH;                 // half2 slot 0..10
        int izz = tid / BSXH;                 // 0..37
        int jb = 0;
        if (izz >= BBZ) { izz -= BBZ; jb = 8; }   // second half: y-rows 8..15
        int si = jb * BBXZ + izz * BBX + 2 * ixh;
        if (BINT) {
            const __half2* g = (const __half2*)
                (T + ((size_t)(loz + izz) * LL + (loy + jb)) * LL + (lox + 2 * ixh));
            #pragma unroll
            for (int j = 0; j < 8; ++j)
                *(float2*)&S[si + j * BBXZ] = __half22float2(g[j * (LL / 2)]);
        } else {
            int gx0 = lox + 2 * ixh, gx1 = gx0 + 1;
            #pragma unroll
            for (int j = 0; j < 8; ++j) {
                int gz = loz + izz, gy = loy + jb + j;
                bool zy = ((unsigned)gz < (unsigned)LL) & ((unsigned)gy < (unsigned)LL);
                size_t rowb = ((size_t)gz * LL + gy) * LL;
                S[si + j * BBXZ]     = (zy && (unsigned)gx0 < (unsigned)LL)
                                     ? __half2float(T[rowb + gx0]) : 0.0f;
                S[si + j * BBXZ + 1] = (zy && (unsigned)gx1 < (unsigned)LL)
                                     ? __half2float(T[rowb + gx1]) : 0.0f;
            }
        }
    }
    __syncthreads();

    int lx = tid & 7, ly = (tid >> 3) & 7, lz = tid >> 6;
    int col = tid & 63;
    int x = ox + lx, y = oy + ly;
    float v0 = 0.0f, v1 = 0.0f;
    if (x < SS && y < SS) {
        float fx = (float)lx - 3.5f, fy = (float)ly - 3.5f, fz = (float)lz - 7.5f;
        float qx = qc.x + fmaf(M.m[0], fx, fmaf(M.m[1], fy, M.m[2] * fz));
        float qy = qc.y + fmaf(M.m[3], fx, fmaf(M.m[4], fy, M.m[5] * fz));
        float qz = qc.z + fmaf(M.m[6], fx, fmaf(M.m[7], fy, M.m[8] * fz));
        int z0 = oz + lz, z1 = oz + 8 + lz;
        if (z0 < SS)
            v0 = tri_back(S, qx, qy, qz, lox, loy, loz)
               * __half2float(W[(z0 * SS + y) * SS + x]);
        if (z1 < SS) {
            float qx2 = qx + 8.0f * M.m[2];
            float qy2 = qy + 8.0f * M.m[5];
            float qz2 = qz + 8.0f * M.m[8];
            v1 = tri_back(S, qx2, qy2, qz2, lox, loy, loz)
               * __half2float(W[(z1 * SS + y) * SS + x]);
        }
    }
    Sc[lz * 64 + col] = v0 + v1;
    __syncthreads();
    if (tid < 64) {
        float s = 0.0f;
        #pragma unroll
        for (int k = 0; k < 8; ++k) s += Sc[k * 64 + tid];
        int xx = ox + (tid & 7), yy = oy + (tid >> 3);
        if (xx < SS && yy < SS) atomicAdd(&A[yy * SS + xx], s);
    }
}

__global__ __launch_bounds__(256) void k_combine(const float* __restrict__ A0,
        const float* __restrict__ A1, float* __restrict__ out, F3 c0, F3 c1) {
    int i = blockIdx.x * 256 + threadIdx.x;
    if (i >= 3 * SS2) return;
    int ch = i / SS2, col = i - ch * SS2;
    float r0 = (ch == 0) ? c0.x : ((ch == 1) ? c0.y : c0.z);
    float r1 = (ch == 0) ? c1.x : ((ch == 1) ? c1.y : c1.z);
    float o = CABS * (A0[col] * r0 + A1[col] * r1);
    out[i] = fminf(fmaxf(o, 0.0f), 1.0f);
}

// ---- minimal-workspace fallback ----
__global__ __launch_bounds__(256) void k_rot_full(const float* __restrict__ d,
                                                  float* __restrict__ T, Mat3 R) {
    int i = blockIdx.x * 256 + threadIdx.x;
    if (i >= LL3) return;
    int x = i % LL; int r = i / LL; int y = r % LL; int z = r / LL;
    float qx, qy, qz; qmap(R, x, y, z, qx, qy, qz);
    T[i] = tri_d_g(d, qz, qy, qx);
}

__global__ __launch_bounds__(256) void k_scan_full(float* __restrict__ T) {
    int col = blockIdx.x * 256 + threadIdx.x;
    if (col >= LL2) return;
    float run = 0.0f;
    for (int z = LL - 1; z >= 0; --z) {
        int idx = z * LL2 + col;
        run += T[idx];
        T[idx] = __expf(-CABS * run);
    }
}

__global__ __launch_bounds__(64) void k_fused_back(const float* __restrict__ T,
        const float* __restrict__ d, float* __restrict__ LA, Mat3 RT,
        float cr, float cg, float cb, int first) {
    int col = blockIdx.x * 64 + threadIdx.x;
    if (col >= SS2) return;
    int y = col / SS, x = col % SS;
    float run = 0.0f, acc = 0.0f;
    for (int z = SS - 1; z >= 0; --z) {
        float qx, qy, qz; qmap(RT, x + PAD, y + PAD, z + PAD, qx, qy, qz);
        float u = tri_T(T, qz, qy, qx);
        float dv = d[z * SS2 + col];
        run += dv;
        acc = fmaf(dv * __expf(-CABS * run), u, acc);
    }
    if (first) {
        LA[0 * SS2 + col] = acc * cr;
        LA[1 * SS2 + col] = acc * cg;
        LA[2 * SS2 + col] = acc * cb;
    } else {
        LA[0 * SS2 + col] += acc * cr;
        LA[1 * SS2 + col] += acc * cg;
        LA[2 * SS2 + col] += acc * cb;
    }
}

__global__ __launch_bounds__(256) void k_clip(const float* __restrict__ LA,
                                              float* __restrict__ out) {
    int i = blockIdx.x * 256 + threadIdx.x;
    if (i < 3 * SS2) out[i] = fminf(fmaxf(CABS * LA[i], 0.0f), 1.0f);
}

static void light_mats(const double ld_in[3], Mat3& R, Mat3& RT) {
    double n = sqrt(ld_in[0]*ld_in[0] + ld_in[1]*ld_in[1] + ld_in[2]*ld_in[2]);
    double l0 = ld_in[0]/n, l1 = ld_in[1]/n, l2 = ld_in[2]/n;
    double yv = -asin(l0);
    if (l2 < 0) yv = -M_PI - yv;
    double yd = yv * 180.0 / M_PI, pd = asin(l1) * 180.0 / M_PI;
    double yr = yd * M_PI / 180.0, pr = pd * M_PI / 180.0;
    float cy = (float)cos(yr), sy = (float)sin(yr), cp = (float)cos(pr), sp = (float)sin(pr);
    float m[9] = { cy,  sy*sp,  sy*cp,
                   0.f, cp,    -sp,
                  -sy,  cy*sp,  cy*cp };
    for (int i = 0; i < 9; ++i) R.m[i] = m[i];
    RT.m[0] = m[0]; RT.m[1] = m[3]; RT.m[2] = m[6];
    RT.m[3] = m[1]; RT.m[4] = m[4]; RT.m[5] = m[7];
    RT.m[6] = m[2]; RT.m[7] = m[5]; RT.m[8] = m[8];
}

static F3 half_span8(const Mat3& M) {
    F3 h;
    h.x = 3.5f * (fabsf(M.m[0]) + fabsf(M.m[1]) + fabsf(M.m[2])) + 0.05f;
    h.y = 3.5f * (fabsf(M.m[3]) + fabsf(M.m[4]) + fabsf(M.m[5])) + 0.05f;
    h.z = 3.5f * (fabsf(M.m[6]) + fabsf(M.m[7]) + fabsf(M.m[8])) + 0.05f;
    return h;
}

static F3 half_span16(const Mat3& M) {
    F3 h;
    h.x = 3.5f * (fabsf(M.m[0]) + fabsf(M.m[1])) + 7.5f * fabsf(M.m[2]) + 0.1f;
    h.y = 3.5f * (fabsf(M.m[3]) + fabsf(M.m[4])) + 7.5f * fabsf(M.m[5]) + 0.1f;
    h.z = 3.5f * (fabsf(M.m[6]) + fabsf(M.m[7])) + 7.5f * fabsf(M.m[8]) + 0.1f;
    return h;
}

static void h_qc16(const Mat3& M, double ox, double oy, double oz, double q[3]) {
    double cb[3] = { (ox + 3.5) * 2.0 / 223.0 - 1.0,
                     (oy + 3.5) * 2.0 / 223.0 - 1.0,
                     (oz + 7.5) * 2.0 / 223.0 - 1.0 };
    for (int k = 0; k < 3; ++k)
        q[k] = ((double)M.m[3*k] * cb[0] + (double)M.m[3*k+1] * cb[1]
              + (double)M.m[3*k+2] * cb[2]) * 111.5 + 111.5;
}

extern "C" void kernel_launch(void* const* d_in, const int* in_sizes, int n_in,
                              void* d_out, int out_size, void* d_ws, size_t ws_size,
                              hipStream_t stream) {
    const float* d = (const float*)d_in[0];
    float* out = (float*)d_out;

    const double dirs[2][3] = { {2.0, 1.0, 1.0}, {-1.0, 0.5, 0.0} };
    F3 c0 = { 1.0f, 69.0f / 255.0f, 25.0f / 255.0f };
    F3 c1 = { 227.0f / 255.0f, 1.0f, 66.0f / 255.0f };
    Mat3 R[2], RT[2];
    light_mats(dirs[0], R[0], RT[0]);
    light_mats(dirs[1], R[1], RT[1]);
    F3 H8[2]  = { half_span8(R[0]),  half_span8(R[1])  };    // Run-table accept8
    F3 H16[2] = { half_span16(R[0]), half_span16(R[1]) };    // k_rot box
    F3 HB[2]  = { half_span16(RT[0]), half_span16(RT[1]) };  // k_back box

    // back-staging boxes provably interior? (mirrors device lox&~1 + x:22)
    bool bint = true;
    for (int l = 0; l < 2 && bint; ++l) {
        double H[3] = { HB[l].x, HB[l].y, HB[l].z };
        int dim[3] = { BBX, BBY, BBZ };
        for (int tz = 0; tz < NBZ16 && bint; ++tz)
            for (int ty = 0; ty < NT3 && bint; ++ty)
                for (int tx = 0; tx < NT3; ++tx) {
                    double q[3]; h_qc16(RT[l], tx * 8 + PAD, ty * 8 + PAD, tz * 16 + PAD, q);
                    for (int k = 0; k < 3; ++k) {
                        int lo = (int)floor(q[k] - H[k]);
                        if (k == 0) lo &= ~1;
                        if (lo < 1 || lo + dim[k] > LL - 1) { bint = false; break; }
                    }
                    if (!bint) break;
                }
    }

    // host-built compact accepted-tile list (superset of device accept:
    // double math + 0.01 margin). Params are fixed -> compute once.
    static int hlist[ROTG + 8];
    static int cnt8 = -1;
    if (cnt8 < 0) {
        int cnt = 0;
        for (int l = 0; l < 2; ++l) {
            double Hx = H16[l].x + 0.01, Hy = H16[l].y + 0.01, Hz = H16[l].z + 0.01;
            for (int tz = 0; tz < NTZ16; ++tz)
                for (int ty = 0; ty < 28; ++ty)
                    for (int tx = 0; tx < 28; ++tx) {
                        double q[3];
                        h_qc16(R[l], tx * 8, ty * 8, tz * 16, q);
                        bool acc = !(q[0] + Hx < BLO || q[0] - Hx > BHI ||
                                     q[1] + Hy < BLO || q[1] - Hy > BHI ||
                                     q[2] + Hz < BLO || q[2] - Hz > BHI);
                        if (acc)
                            hlist[cnt++] = ((l * NTZ16 + tz) * 28 + ty) * 28 + tx;
                    }
        }
        cnt8 = (cnt + 7) & ~7;
        for (int i = cnt; i < cnt8; ++i) hlist[i] = -1;
    }
    const int cpx = cnt8 / 8;

    // layout: f32 blocks (S0, S1, Dseg, A0, A1, List; padded), then halves
    // (W [padded], T0, T1 — 16B-aligned), then Run
    const size_t f32n = (size_t)(2 * NTZ * LL2 + NSEG * SS2 + 2 * SS2) + ROTG + 8;
    const size_t f32p = (f32n + 3) & ~(size_t)3;          // 16B-align W
    const size_t ss3p = ((size_t)SS3 + 7) & ~(size_t)7;   // 16B-align T0
    const size_t need_A = f32p * 4 + (ss3p + 2 * LL3) * 2 + 2 * 784 * 2; // ~62 MB
    const size_t need_C = (size_t)(LL3 + 3 * SS2) * 4;                   // ~45 MB

    if (ws_size >= need_A) {
        float* S0   = (float*)d_ws;
        float* S1   = S0 + NTZ * LL2;
        float* Dseg = S1 + NTZ * LL2;
        float* A0   = Dseg + NSEG * SS2;
        float* A1   = A0 + SS2;
        int*   Lst  = (int*)(A1 + SS2);
        __half* W   = (__half*)((float*)d_ws + f32p);
        __half* T0  = W + ss3p;
        __half* T1  = T0 + LL3;
        unsigned short* Run = (unsigned short*)(T1 + LL3);

        (void)hipMemcpyAsync(Lst, hlist, (size_t)cnt8 * sizeof(int),
                             hipMemcpyHostToDevice, stream);
        k_rot  <<<EXB + cnt8, 512, 0, stream>>>(d, T0, T1, S0, S1, Dseg, A0,
                                                Run, Lst, cpx,
                                                R[0], R[1], H16[0], H16[1],
                                                H8[0], H8[1]);
        k_mid  <<<MIDG, 256, 0, stream>>>(T0, T1, S0, S1, Run, d, Dseg, W);
        if (bint)
            k_back<true><<<BACKG_P, 512, 0, stream>>>(T0, T1, W, A0, A1,
                                                      RT[0], RT[1], HB[0], HB[1]);
        else
            k_back<false><<<BACKG_P, 512, 0, stream>>>(T0, T1, W, A0, A1,
                                                       RT[0], RT[1], HB[0], HB[1]);
        k_combine<<<(3 * SS2 + 255) / 256, 256, 0, stream>>>(A0, A1, out, c0, c1);
    } else if (ws_size >= need_C) {
        float* T  = (float*)d_ws;
        float* LA = T + LL3;
        for (int l = 0; l < 2; ++l) {
            k_rot_full <<<(LL3 + 255) / 256, 256, 0, stream>>>(d, T, R[l]);
            k_scan_full<<<(LL2 + 255) / 256, 256, 0, stream>>>(T);
            k_fused_back<<<(SS2 + 63) / 64, 64, 0, stream>>>(T, d, LA, RT[l],
                l ? c1.x : c0.x, l ? c1.y : c0.y, l ? c1.z : c0.z, l == 0);
        }
        k_clip<<<(3 * SS2 + 255) / 256, 256, 0, stream>>>(LA, out);
    }
}

// Round 17
// 168.466 us; speedup vs baseline: 1.1411x; 1.1411x over previous
//
#include <hip/hip_runtime.h>
#include <hip/hip_fp16.h>
#include <math.h>
#include <stdint.h>

#ifndef M_PI
#define M_PI 3.14159265358979323846
#endif

#define SS   129
#define LL   224
#define LL2  (LL*LL)
#define LLQ  (LL2/4)
#define LL3  (LL*LL*LL)
#define SS2  (SS*SS)
#define SS3  (SS*SS*SS)
#define CABS 0.2f
#define PAD  48

#define BLO 45.5f
#define BHI 178.5f

#define NT1  28                  // 8-tile grid per axis (Run granularity)
#define NTZ16 14                 // 16-deep rot super-tiles along z
#define ROTG  (2 * NTZ16 * 784)  // 21952 logical rot super-tiles
#define NT3  17
#define NBZ16 9                  // 16-deep back super-tiles
#define BACKG (2 * NBZ16 * 289)  // 5202 logical back blocks
#define BACKCH 17                // k_back swizzle chunk
#define BACKG_P 5304             // padded: 8*39*17
#define NTZ  28

// view-ray segmentation: 16 segs of 9
#define NSEG 16
#define SEGZ 9
#define DSEGT (NSEG * SS2)                 // 266256
// k_rot pre-work blocks, dispatched FIRST:
#define EXB1 ((DSEGT + 511) / 512)         // 521: Dseg sums + A zero
#define EXB2 4                             // Run-table build
#define EXB  (EXB1 + EXB2)
// k_mid: 2744 texp blocks (one thread per tile-colQUAD) + 1041 W blocks
#define TXB4 (2 * NTZ * LLQ / 256)         // 2744 exact
#define PREB1 ((DSEGT + 255) / 256)        // 1041
#define MIDG (TXB4 + PREB1)
// k_list: per-thread contiguous chunk of logical tiles
#define LPER ((ROTG + 511) / 512)          // 43

// k_rot staging box: [y:16][z:18][x:22] (x stride 1, z stride 22, y stride 396)
#define RBX 22
#define RBY 16
#define RBZ 18
#define RBXZ (RBX*RBZ)           // 396
#define RBN (RBX*RBY*RBZ)        // 6336 words
#define RSXH 11                  // float2 slots per row

// k_back staging box: [y:16][z:19][x:22] (x stride 1, z stride 22, y stride 418)
#define BBX 22
#define BBY 16
#define BBZ 19
#define BBXZ (BBX*BBZ)           // 418
#define BBN (BBX*BBY*BBZ)        // 6688 words
#define BSXH 11                  // half2 slots per row

struct Mat3 { float m[9]; };
struct F3   { float x, y, z; };

__device__ __forceinline__ F3 tile_center(const Mat3& M, int ox, int oy, int oz) {
    float cbx = fmaf((float)ox + 3.5f, 2.0f / 223.0f, -1.0f);
    float cby = fmaf((float)oy + 3.5f, 2.0f / 223.0f, -1.0f);
    float cbz = fmaf((float)oz + 3.5f, 2.0f / 223.0f, -1.0f);
    F3 qc;
    qc.x = fmaf(fmaf(M.m[0], cbx, fmaf(M.m[1], cby, M.m[2] * cbz)), 111.5f, 111.5f);
    qc.y = fmaf(fmaf(M.m[3], cbx, fmaf(M.m[4], cby, M.m[5] * cbz)), 111.5f, 111.5f);
    qc.z = fmaf(fmaf(M.m[6], cbx, fmaf(M.m[7], cby, M.m[8] * cbz)), 111.5f, 111.5f);
    return qc;
}

__device__ __forceinline__ F3 tile_center16(const Mat3& M, int ox, int oy, int oz) {
    float cbx = fmaf((float)ox + 3.5f, 2.0f / 223.0f, -1.0f);
    float cby = fmaf((float)oy + 3.5f, 2.0f / 223.0f, -1.0f);
    float cbz = fmaf((float)oz + 7.5f, 2.0f / 223.0f, -1.0f);
    F3 qc;
    qc.x = fmaf(fmaf(M.m[0], cbx, fmaf(M.m[1], cby, M.m[2] * cbz)), 111.5f, 111.5f);
    qc.y = fmaf(fmaf(M.m[3], cbx, fmaf(M.m[4], cby, M.m[5] * cbz)), 111.5f, 111.5f);
    qc.z = fmaf(fmaf(M.m[6], cbx, fmaf(M.m[7], cby, M.m[8] * cbz)), 111.5f, 111.5f);
    return qc;
}

__device__ __forceinline__ bool tile_accept(F3 qc, F3 H) {
    return !(qc.x + H.x < BLO || qc.x - H.x > BHI ||
             qc.y + H.y < BLO || qc.y - H.y > BHI ||
             qc.z + H.z < BLO || qc.z - H.z > BHI);
}

__device__ __forceinline__ void qmap(const Mat3& M, int x, int y, int z,
                                     float& qx, float& qy, float& qz) {
    float bx = fmaf((float)x, 2.0f / 223.0f, -1.0f);
    float by = fmaf((float)y, 2.0f / 223.0f, -1.0f);
    float bz = fmaf((float)z, 2.0f / 223.0f, -1.0f);
    qx = fmaf(fmaf(M.m[0], bx, fmaf(M.m[1], by, M.m[2] * bz)), 111.5f, 111.5f);
    qy = fmaf(fmaf(M.m[3], bx, fmaf(M.m[4], by, M.m[5] * bz)), 111.5f, 111.5f);
    qz = fmaf(fmaf(M.m[6], bx, fmaf(M.m[7], by, M.m[8] * bz)), 111.5f, 111.5f);
}

__device__ __forceinline__ float fetch_d(const float* __restrict__ d, int z, int y, int x) {
    unsigned zz = (unsigned)(z - PAD), yy = (unsigned)(y - PAD), xx = (unsigned)(x - PAD);
    return (zz < (unsigned)SS && yy < (unsigned)SS && xx < (unsigned)SS)
        ? d[((int)zz * SS + (int)yy) * SS + (int)xx] : 0.0f;
}

__device__ __forceinline__ float fetch_T(const float* __restrict__ T, int z, int y, int x) {
    unsigned zz = (unsigned)z, yy = (unsigned)y, xx = (unsigned)x;
    return (zz < (unsigned)LL && yy < (unsigned)LL && xx < (unsigned)LL)
        ? T[((int)zz * LL + (int)yy) * LL + (int)xx] : 0.0f;
}

__device__ __forceinline__ float tri_T(const float* __restrict__ T, float qz, float qy, float qx) {
    int x0 = (int)floorf(qx), y0 = (int)floorf(qy), z0 = (int)floorf(qz);
    float wx = qx - (float)x0, wy = qy - (float)y0, wz = qz - (float)z0;
    float c000 = fetch_T(T, z0, y0, x0),     c001 = fetch_T(T, z0, y0, x0 + 1);
    float c010 = fetch_T(T, z0, y0 + 1, x0), c011 = fetch_T(T, z0, y0 + 1, x0 + 1);
    float c100 = fetch_T(T, z0 + 1, y0, x0),     c101 = fetch_T(T, z0 + 1, y0, x0 + 1);
    float c110 = fetch_T(T, z0 + 1, y0 + 1, x0), c111 = fetch_T(T, z0 + 1, y0 + 1, x0 + 1);
    float a00 = c000 + wx * (c001 - c000), a01 = c010 + wx * (c011 - c010);
    float a10 = c100 + wx * (c101 - c100), a11 = c110 + wx * (c111 - c110);
    float b0 = a00 + wy * (a01 - a00), b1 = a10 + wy * (a11 - a10);
    return b0 + wz * (b1 - b0);
}

__device__ __forceinline__ float tri_d_g(const float* __restrict__ d, float qz, float qy, float qx) {
    int x0 = (int)floorf(qx), y0 = (int)floorf(qy), z0 = (int)floorf(qz);
    float wx = qx - (float)x0, wy = qy - (float)y0, wz = qz - (float)z0;
    float c000 = fetch_d(d, z0, y0, x0),     c001 = fetch_d(d, z0, y0, x0 + 1);
    float c010 = fetch_d(d, z0, y0 + 1, x0), c011 = fetch_d(d, z0, y0 + 1, x0 + 1);
    float c100 = fetch_d(d, z0 + 1, y0, x0),     c101 = fetch_d(d, z0 + 1, y0, x0 + 1);
    float c110 = fetch_d(d, z0 + 1, y0 + 1, x0), c111 = fetch_d(d, z0 + 1, y0 + 1, x0 + 1);
    float a00 = c000 + wx * (c001 - c000), a01 = c010 + wx * (c011 - c010);
    float a10 = c100 + wx * (c101 - c100), a11 = c110 + wx * (c111 - c110);
    float b0 = a00 + wy * (a01 - a00), b1 = a10 + wy * (a11 - a10);
    return b0 + wz * (b1 - b0);
}

// trilinear from k_rot's [y:16][z:18][x:22] box (strides 396 / 22 / 1)
__device__ __forceinline__ float tri_rot(const float* __restrict__ S,
                                         float qx, float qy, float qz,
                                         int lox, int loy, int loz) {
    int x0 = (int)floorf(qx), y0 = (int)floorf(qy), z0 = (int)floorf(qz);
    float wx = qx - (float)x0, wy = qy - (float)y0, wz = qz - (float)z0;
    int i = (y0 - loy) * RBXZ + (z0 - loz) * RBX + (x0 - lox);
    float c000 = S[i],         c001 = S[i + 1];
    float cz0  = S[i + 22],    cz1  = S[i + 23];
    float cy0  = S[i + 396],   cy1  = S[i + 397];
    float cw0  = S[i + 418],   cw1  = S[i + 419];
    float a00 = c000 + wx * (c001 - c000);
    float a01 = cy0  + wx * (cy1  - cy0);
    float a10 = cz0  + wx * (cz1  - cz0);
    float a11 = cw0  + wx * (cw1  - cw0);
    float b0  = a00 + wy * (a01 - a00);
    float b1  = a10 + wy * (a11 - a10);
    return b0 + wz * (b1 - b0);
}

// trilinear from k_back's [y:16][z:19][x:22] box (strides 418 / 22 / 1)
__device__ __forceinline__ float tri_back(const float* __restrict__ S,
                                          float qx, float qy, float qz,
                                          int lox, int loy, int loz) {
    int x0 = (int)floorf(qx), y0 = (int)floorf(qy), z0 = (int)floorf(qz);
    float wx = qx - (float)x0, wy = qy - (float)y0, wz = qz - (float)z0;
    int i = (y0 - loy) * BBXZ + (z0 - loz) * BBX + (x0 - lox);
    float c000 = S[i],         c001 = S[i + 1];
    float cz0  = S[i + 22],    cz1  = S[i + 23];
    float cy0  = S[i + 418],   cy1  = S[i + 419];
    float cw0  = S[i + 440],   cw1  = S[i + 441];
    float a00 = c000 + wx * (c001 - c000);
    float a01 = cy0  + wx * (cy1  - cy0);
    float a10 = cz0  + wx * (cz1  - cz0);
    float a11 = cw0  + wx * (cw1  - cw0);
    float b0  = a00 + wy * (a01 - a00);
    float b1  = a10 + wy * (a11 - a10);
    return b0 + wz * (b1 - b0);
}

// k_list: build the compacted accepted-tile list ON DEVICE (no H2D copy).
// 1 block, 512 threads. Thread t accept-tests logical tiles
// [t*LPER, (t+1)*LPER) with the SAME float test k_rot used inline (r13 set),
// thread-0 serial scan for offsets, ordered compact write, sentinel tail.
__global__ __launch_bounds__(512) void k_list(int* __restrict__ List, int cnt8,
        Mat3 M0, Mat3 M1, F3 H0, F3 H1) {
    __shared__ int cnts[512];
    __shared__ int offs[513];
    int tid = threadIdx.x;
    int base = tid * LPER;
    int cnt = 0;
    for (int i = 0; i < LPER; ++i) {
        int b = base + i;
        if (b >= ROTG) break;
        int light = b / (NTZ16 * 784);
        int r = b - light * (NTZ16 * 784);
        int tz16 = r / 784;
        int r2 = r - tz16 * 784;
        int tty = r2 / 28, ttx = r2 - tty * 28;
        const Mat3 M = light ? M1 : M0;
        const F3  H  = light ? H1 : H0;
        F3 qc = tile_center16(M, ttx * 8, tty * 8, tz16 * 16);
        if (tile_accept(qc, H)) ++cnt;
    }
    cnts[tid] = cnt;
    __syncthreads();
    if (tid == 0) {
        int s = 0;
        for (int i = 0; i < 512; ++i) { offs[i] = s; s += cnts[i]; }
        offs[512] = s;
    }
    __syncthreads();
    int o = offs[tid];
    for (int i = 0; i < LPER; ++i) {
        int b = base + i;
        if (b >= ROTG) break;
        int light = b / (NTZ16 * 784);
        int r = b - light * (NTZ16 * 784);
        int tz16 = r / 784;
        int r2 = r - tz16 * 784;
        int tty = r2 / 28, ttx = r2 - tty * 28;
        const Mat3 M = light ? M1 : M0;
        const F3  H  = light ? H1 : H0;
        F3 qc = tile_center16(M, ttx * 8, tty * 8, tz16 * 16);
        if (tile_accept(qc, H)) List[o++] = b;
    }
    int total = offs[512];
    for (int i = total + tid; i < cnt8; i += 512) List[i] = -1;
}

// K1: pre-work blocks FIRST [0,EXB): Dseg sums + A zero + Run table.
// Blocks [EXB, EXB+cnt8): COMPACTED accepted super-tiles via device-built
// List (sentinel -1 pads). Bijective chunked XCD swizzle on the compact
// index space. float2 staging (396 threads = 2 per (z,slot), 8 y-rows each;
// lox even), raw-sample packed T store + per-tile Ssum totals.
__global__ __launch_bounds__(512) void k_rot(const float* __restrict__ d,
        __half* __restrict__ T0, __half* __restrict__ T1,
        float* __restrict__ S0, float* __restrict__ S1,
        float* __restrict__ Dseg, float* __restrict__ A,
        unsigned short* __restrict__ Run, const int* __restrict__ List, int cpx,
        Mat3 M0, Mat3 M1, F3 H0, F3 H1, F3 G0, F3 G1) {
    int n = blockIdx.x;
    int tid = threadIdx.x;
    if (n < EXB) {                          // ---- pre-work ----
        if (n < EXB1) {
            int t = n * 512 + tid;
            if (t < 2 * SS2) A[t] = 0.0f;
            if (t >= DSEGT) return;
            int seg = t / SS2, col = t - seg * SS2;
            int zs = seg * SEGZ, ze = min(SS, zs + SEGZ);
            float run = 0.0f;
            for (int z = zs; z < ze; ++z) run += d[z * SS2 + col];
            Dseg[t] = run;
        } else {
            int id = (n - EXB1) * 512 + tid;
            if (id >= 2 * 784) return;
            int l = id / 784, r = id - l * 784;
            int ty = r / 28, tx = r - ty * 28;
            const Mat3 M = l ? M1 : M0;
            const F3  G  = l ? G1 : G0;
            int t0 = -1, t1 = -1;
            for (int tz = 0; tz < NT1; ++tz) {
                F3 qc = tile_center(M, tx * 8, ty * 8, tz * 8);
                if (tile_accept(qc, G)) { if (t0 < 0) t0 = tz; t1 = tz; }
            }
            Run[id] = (t0 < 0) ? 0xFFFFu : (unsigned short)(t0 | (t1 << 8));
        }
        return;
    }

    int nn = n - EXB;
    int x8 = nn & 7, i8 = nn >> 3;          // XCD, sequence-within-XCD
    int b = List[x8 * cpx + i8];            // compact -> logical id
    if (b < 0) return;                      // pad sentinel

    int light = b / (NTZ16 * 784);
    int r = b - light * (NTZ16 * 784);
    int tz16 = r / 784;
    int r2 = r - tz16 * 784;
    int tty = r2 / 28, ttx = r2 - tty * 28;

    const Mat3 M = light ? M1 : M0;
    const F3  H  = light ? H1 : H0;           // H16
    __half* __restrict__ T   = light ? T1 : T0;
    float* __restrict__ Ssum = light ? S1 : S0;

    int ox = ttx * 8, oy = tty * 8, oz = tz16 * 16;
    F3 qc = tile_center16(M, ox, oy, oz);

    int lox = (int)floorf(qc.x - H.x);
    lox &= ~1;                                // even for float2 staging
    int loy = (int)floorf(qc.y - H.y);
    int loz = (int)floorf(qc.z - H.z);

    __shared__ float S[RBN];
    __shared__ float Sc[1024];

    if (tid < 2 * RSXH * RBZ) {               // 396 staging threads
        int ixh = tid % RSXH;                 // float2 slot 0..10
        int izz = tid / RSXH;                 // 0..35
        int jb = 0;
        if (izz >= RBZ) { izz -= RBZ; jb = 8; }   // second half: y-rows 8..15
        bool interior = (lox >= PAD) & (lox <= PAD + SS - RBX) &
                        (loy >= PAD) & (loy <= PAD + SS - RBY) &
                        (loz >= PAD) & (loz <= PAD + SS - RBZ);
        int si = jb * RBXZ + izz * RBX + 2 * ixh;
        if (interior) {
            const float* g = d + ((size_t)(loz + izz - PAD) * SS + (loy + jb - PAD)) * SS
                               + (lox + 2 * ixh - PAD);
            #pragma unroll
            for (int j = 0; j < 8; ++j)
                *(float2*)&S[si + j * RBXZ] = *(const float2*)&g[j * SS];
        } else {
            int gx0 = lox + 2 * ixh;
            #pragma unroll
            for (int j = 0; j < 8; ++j) {
                S[si + j * RBXZ]     = fetch_d(d, loz + izz, loy + jb + j, gx0);
                S[si + j * RBXZ + 1] = fetch_d(d, loz + izz, loy + jb + j, gx0 + 1);
            }
        }
    }
    __syncthreads();

    int lx = tid & 7, ly = (tid >> 3) & 7, lz = tid >> 6;
    int col = tid & 63;
    float fx = (float)lx - 3.5f, fy = (float)ly - 3.5f, fz = (float)lz - 7.5f;
    float qx = qc.x + fmaf(M.m[0], fx, fmaf(M.m[1], fy, M.m[2] * fz));
    float qy = qc.y + fmaf(M.m[3], fx, fmaf(M.m[4], fy, M.m[5] * fz));
    float qz = qc.z + fmaf(M.m[6], fx, fmaf(M.m[7], fy, M.m[8] * fz));
    float v0 = tri_rot(S, qx, qy, qz, lox, loy, loz);
    float qx2 = qx + 8.0f * M.m[2];
    float qy2 = qy + 8.0f * M.m[5];
    float qz2 = qz + 8.0f * M.m[8];
    float v1 = tri_rot(S, qx2, qy2, qz2, lox, loy, loz);

    Sc[lz * 64 + col] = v0;
    Sc[(lz + 8) * 64 + col] = v1;
    __syncthreads();
    // merged read-only tail: waves 0-1 pack raw T rows; waves 2-3 Ssum totals
    if (tid < 128) {
        int zz = tid >> 3, ly2 = tid & 7;
        const float4* Sc4 = (const float4*)Sc;
        float4 f0 = Sc4[zz * 16 + ly2 * 2];
        float4 f1 = Sc4[zz * 16 + ly2 * 2 + 1];
        union { __half2 h[4]; float4 v; } u;
        u.h[0] = __floats2half2_rn(f0.x, f0.y);
        u.h[1] = __floats2half2_rn(f0.z, f0.w);
        u.h[2] = __floats2half2_rn(f1.x, f1.y);
        u.h[3] = __floats2half2_rn(f1.z, f1.w);
        *(float4*)&T[(size_t)(oz + zz) * LL2 + (oy + ly2) * LL + ox] = u.v;
    } else if (tid < 256) {
        int t2 = tid - 128;
        int cc = t2 & 63, h = t2 >> 6;      // h=0: lower 8-tile, h=1: upper
        float s = 0.0f;
        #pragma unroll
        for (int k = 0; k < 8; ++k) s += Sc[(h * 8 + k) * 64 + cc];
        int so = (oy + (cc >> 3)) * LL + (ox + (cc & 7));
        Ssum[(2 * tz16 + h) * LL2 + so] = s;
    }
}

// k_mid: blocks [0,TXB4): transmittance. One thread per (light, tile,
//   column-QUAD): single Run lookup, inline cross-tile suffix via float4
//   Ssum-totals loads (L2-resident, r13-proven), T via float2 (4 halves)
//   loads/stores, in-register 8-deep suffix + exp, in place.
//   blocks [TXB4,MIDG): W write (fp16) from d + Dseg.
__global__ __launch_bounds__(256) void k_mid(__half* __restrict__ T0,
        __half* __restrict__ T1, const float* __restrict__ S0,
        const float* __restrict__ S1, const unsigned short* __restrict__ Run,
        const float* __restrict__ d, const float* __restrict__ Dseg,
        __half* __restrict__ W) {
    int b = blockIdx.x;
    if (b < TXB4) {
        int id = b * 256 + threadIdx.x;        // < 2*NTZ*LLQ exactly
        int light = id / (NTZ * LLQ);
        int r = id - light * (NTZ * LLQ);
        int t = r / LLQ, cq = r - t * LLQ;
        int col = cq * 4;
        int y = col / LL, x = col - y * LL;    // x mult of 4 -> one 8-tile
        unsigned short rt = Run[light * 784 + (y >> 3) * 28 + (x >> 3)];
        if (rt == 0xFFFFu) return;
        int t0 = rt & 0xFF, t1 = rt >> 8;
        if (t < t0 || t > t1) return;
        const float* __restrict__ Ssum = light ? S1 : S0;
        float oA = 0.0f, oB = 0.0f, oC = 0.0f, oD = 0.0f;
        for (int tp = t + 1; tp <= t1; ++tp) {
            float4 s4 = *(const float4*)&Ssum[tp * LL2 + col];  // 16B aligned
            oA += s4.x; oB += s4.y; oC += s4.z; oD += s4.w;
        }
        float2* __restrict__ Tp =
            (float2*)((__half*)(light ? T1 : T0) + (size_t)(8 * t) * LL2 + col);
        float2 raw[8];
        #pragma unroll
        for (int k = 0; k < 8; ++k) raw[k] = Tp[k * LLQ];   // 4 halves each
        float4 v[8];
        #pragma unroll
        for (int k = 0; k < 8; ++k) {
            __half2 h0 = ((__half2*)&raw[k])[0];
            __half2 h1 = ((__half2*)&raw[k])[1];
            float2 f0 = __half22float2(h0), f1 = __half22float2(h1);
            v[k] = make_float4(f0.x, f0.y, f1.x, f1.y);
        }
        float sA = oA, sB = oB, sC = oC, sD = oD;
        #pragma unroll
        for (int k = 7; k >= 0; --k) {
            sA += v[k].x; sB += v[k].y; sC += v[k].z; sD += v[k].w;
            v[k].x = sA; v[k].y = sB; v[k].z = sC; v[k].w = sD;
        }
        #pragma unroll
        for (int k = 0; k < 8; ++k) {
            __half2 h0 = __floats2half2_rn(__expf(-CABS * v[k].x),
                                           __expf(-CABS * v[k].y));
            __half2 h1 = __floats2half2_rn(__expf(-CABS * v[k].z),
                                           __expf(-CABS * v[k].w));
            float2 o;
            ((__half2*)&o)[0] = h0;
            ((__half2*)&o)[1] = h1;
            Tp[k * LLQ] = o;
        }
    } else {
        int t = (b - TXB4) * 256 + threadIdx.x;
        if (t >= DSEGT) return;
        int seg = t / SS2, col = t - seg * SS2;
        int zs = seg * SEGZ, ze = min(SS, zs + SEGZ);
        float run = 0.0f;
        for (int s2 = seg + 1; s2 < NSEG; ++s2) run += Dseg[s2 * SS2 + col];
        for (int z = ze - 1; z >= zs; --z) {
            float dv = d[z * SS2 + col];
            run += dv;
            W[z * SS2 + col] = __float2half(dv * __expf(-CABS * run));
        }
    }
}

// K3: 8x8x16 super-tile; half2 staging of transmittance (418 threads = 2 per
// (z,slot), 8 y-rows each; lox even), back-rotate, *W16, reduce.
// XCD-chunked swizzle, padded grid.
template<bool BINT>
__global__ __launch_bounds__(512) void k_back(const __half* __restrict__ T0,
        const __half* __restrict__ T1, const __half* __restrict__ W,
        float* __restrict__ A0, float* __restrict__ A1,
        Mat3 M0, Mat3 M1, F3 H0, F3 H1) {
    int n = blockIdx.x;
    int x8 = n & 7, i8 = n >> 3;
    int c = i8 / BACKCH, off = i8 - c * BACKCH;
    int lb = (c * 8 + x8) * BACKCH + off;
    if (lb >= BACKG) return;

    int light = lb / (NBZ16 * 289); lb -= light * (NBZ16 * 289);
    int tz16 = lb / 289;
    int r2 = lb - tz16 * 289;
    int tty = r2 / 17, ttx = r2 - tty * 17;

    const Mat3 M = light ? M1 : M0;
    const F3  H  = light ? H1 : H0;
    const __half* __restrict__ T = light ? T1 : T0;
    float* __restrict__ A = light ? A1 : A0;

    int ox = ttx * 8, oy = tty * 8, oz = tz16 * 16;
    F3 qc = tile_center16(M, ox + PAD, oy + PAD, oz + PAD);
    int lox = (int)floorf(qc.x - H.x);
    lox &= ~1;                                // even for half2 staging
    int loy = (int)floorf(qc.y - H.y);
    int loz = (int)floorf(qc.z - H.z);

    __shared__ float S[BBN];
    __shared__ float Sc[512];
    int tid = threadIdx.x;

    if (tid < 2 * BSXH * BBZ) {               // 418 staging threads
        int ixh = tid % BSXH;                 // half2 slot 0..10
        int izz = tid / BSXH;                 // 0..37
        int jb = 0;
        if (izz >= BBZ) { izz -= BBZ; jb = 8; }   // second half: y-rows 8..15
        int si = jb * BBXZ + izz * BBX + 2 * ixh;
        if (BINT) {
            const __half2* g = (const __half2*)
                (T + ((size_t)(loz + izz) * LL + (loy + jb)) * LL + (lox + 2 * ixh));
            #pragma unroll
            for (int j = 0; j < 8; ++j)
                *(float2*)&S[si + j * BBXZ] = __half22float2(g[j * (LL / 2)]);
        } else {
            int gx0 = lox + 2 * ixh, gx1 = gx0 + 1;
            #pragma unroll
            for (int j = 0; j < 8; ++j) {
                int gz = loz + izz, gy = loy + jb + j;
                bool zy = ((unsigned)gz < (unsigned)LL) & ((unsigned)gy < (unsigned)LL);
                size_t rowb = ((size_t)gz * LL + gy) * LL;
                S[si + j * BBXZ]     = (zy && (unsigned)gx0 < (unsigned)LL)
                                     ? __half2float(T[rowb + gx0]) : 0.0f;
                S[si + j * BBXZ + 1] = (zy && (unsigned)gx1 < (unsigned)LL)
                                     ? __half2float(T[rowb + gx1]) : 0.0f;
            }
        }
    }
    __syncthreads();

    int lx = tid & 7, ly = (tid >> 3) & 7, lz = tid >> 6;
    int col = tid & 63;
    int x = ox + lx, y = oy + ly;
    float v0 = 0.0f, v1 = 0.0f;
    if (x < SS && y < SS) {
        float fx = (float)lx - 3.5f, fy = (float)ly - 3.5f, fz = (float)lz - 7.5f;
        float qx = qc.x + fmaf(M.m[0], fx, fmaf(M.m[1], fy, M.m[2] * fz));
        float qy = qc.y + fmaf(M.m[3], fx, fmaf(M.m[4], fy, M.m[5] * fz));
        float qz = qc.z + fmaf(M.m[6], fx, fmaf(M.m[7], fy, M.m[8] * fz));
        int z0 = oz + lz, z1 = oz + 8 + lz;
        if (z0 < SS)
            v0 = tri_back(S, qx, qy, qz, lox, loy, loz)
               * __half2float(W[(z0 * SS + y) * SS + x]);
        if (z1 < SS) {
            float qx2 = qx + 8.0f * M.m[2];
            float qy2 = qy + 8.0f * M.m[5];
            float qz2 = qz + 8.0f * M.m[8];
            v1 = tri_back(S, qx2, qy2, qz2, lox, loy, loz)
               * __half2float(W[(z1 * SS + y) * SS + x]);
        }
    }
    Sc[lz * 64 + col] = v0 + v1;
    __syncthreads();
    if (tid < 64) {
        float s = 0.0f;
        #pragma unroll
        for (int k = 0; k < 8; ++k) s += Sc[k * 64 + tid];
        int xx = ox + (tid & 7), yy = oy + (tid >> 3);
        if (xx < SS && yy < SS) atomicAdd(&A[yy * SS + xx], s);
    }
}

__global__ __launch_bounds__(256) void k_combine(const float* __restrict__ A0,
        const float* __restrict__ A1, float* __restrict__ out, F3 c0, F3 c1) {
    int i = blockIdx.x * 256 + threadIdx.x;
    if (i >= 3 * SS2) return;
    int ch = i / SS2, col = i - ch * SS2;
    float r0 = (ch == 0) ? c0.x : ((ch == 1) ? c0.y : c0.z);
    float r1 = (ch == 0) ? c1.x : ((ch == 1) ? c1.y : c1.z);
    float o = CABS * (A0[col] * r0 + A1[col] * r1);
    out[i] = fminf(fmaxf(o, 0.0f), 1.0f);
}

// ---- minimal-workspace fallback ----
__global__ __launch_bounds__(256) void k_rot_full(const float* __restrict__ d,
                                                  float* __restrict__ T, Mat3 R) {
    int i = blockIdx.x * 256 + threadIdx.x;
    if (i >= LL3) return;
    int x = i % LL; int r = i / LL; int y = r % LL; int z = r / LL;
    float qx, qy, qz; qmap(R, x, y, z, qx, qy, qz);
    T[i] = tri_d_g(d, qz, qy, qx);
}

__global__ __launch_bounds__(256) void k_scan_full(float* __restrict__ T) {
    int col = blockIdx.x * 256 + threadIdx.x;
    if (col >= LL2) return;
    float run = 0.0f;
    for (int z = LL - 1; z >= 0; --z) {
        int idx = z * LL2 + col;
        run += T[idx];
        T[idx] = __expf(-CABS * run);
    }
}

__global__ __launch_bounds__(64) void k_fused_back(const float* __restrict__ T,
        const float* __restrict__ d, float* __restrict__ LA, Mat3 RT,
        float cr, float cg, float cb, int first) {
    int col = blockIdx.x * 64 + threadIdx.x;
    if (col >= SS2) return;
    int y = col / SS, x = col % SS;
    float run = 0.0f, acc = 0.0f;
    for (int z = SS - 1; z >= 0; --z) {
        float qx, qy, qz; qmap(RT, x + PAD, y + PAD, z + PAD, qx, qy, qz);
        float u = tri_T(T, qz, qy, qx);
        float dv = d[z * SS2 + col];
        run += dv;
        acc = fmaf(dv * __expf(-CABS * run), u, acc);
    }
    if (first) {
        LA[0 * SS2 + col] = acc * cr;
        LA[1 * SS2 + col] = acc * cg;
        LA[2 * SS2 + col] = acc * cb;
    } else {
        LA[0 * SS2 + col] += acc * cr;
        LA[1 * SS2 + col] += acc * cg;
        LA[2 * SS2 + col] += acc * cb;
    }
}

__global__ __launch_bounds__(256) void k_clip(const float* __restrict__ LA,
                                              float* __restrict__ out) {
    int i = blockIdx.x * 256 + threadIdx.x;
    if (i < 3 * SS2) out[i] = fminf(fmaxf(CABS * LA[i], 0.0f), 1.0f);
}

static void light_mats(const double ld_in[3], Mat3& R, Mat3& RT) {
    double n = sqrt(ld_in[0]*ld_in[0] + ld_in[1]*ld_in[1] + ld_in[2]*ld_in[2]);
    double l0 = ld_in[0]/n, l1 = ld_in[1]/n, l2 = ld_in[2]/n;
    double yv = -asin(l0);
    if (l2 < 0) yv = -M_PI - yv;
    double yd = yv * 180.0 / M_PI, pd = asin(l1) * 180.0 / M_PI;
    double yr = yd * M_PI / 180.0, pr = pd * M_PI / 180.0;
    float cy = (float)cos(yr), sy = (float)sin(yr), cp = (float)cos(pr), sp = (float)sin(pr);
    float m[9] = { cy,  sy*sp,  sy*cp,
                   0.f, cp,    -sp,
                  -sy,  cy*sp,  cy*cp };
    for (int i = 0; i < 9; ++i) R.m[i] = m[i];
    RT.m[0] = m[0]; RT.m[1] = m[3]; RT.m[2] = m[6];
    RT.m[3] = m[1]; RT.m[4] = m[4]; RT.m[5] = m[7];
    RT.m[6] = m[2]; RT.m[7] = m[5]; RT.m[8] = m[8];
}

static F3 half_span8(const Mat3& M) {
    F3 h;
    h.x = 3.5f * (fabsf(M.m[0]) + fabsf(M.m[1]) + fabsf(M.m[2])) + 0.05f;
    h.y = 3.5f * (fabsf(M.m[3]) + fabsf(M.m[4]) + fabsf(M.m[5])) + 0.05f;
    h.z = 3.5f * (fabsf(M.m[6]) + fabsf(M.m[7]) + fabsf(M.m[8])) + 0.05f;
    return h;
}

static F3 half_span16(const Mat3& M) {
    F3 h;
    h.x = 3.5f * (fabsf(M.m[0]) + fabsf(M.m[1])) + 7.5f * fabsf(M.m[2]) + 0.1f;
    h.y = 3.5f * (fabsf(M.m[3]) + fabsf(M.m[4])) + 7.5f * fabsf(M.m[5]) + 0.1f;
    h.z = 3.5f * (fabsf(M.m[6]) + fabsf(M.m[7])) + 7.5f * fabsf(M.m[8]) + 0.1f;
    return h;
}

static void h_qc16(const Mat3& M, double ox, double oy, double oz, double q[3]) {
    double cb[3] = { (ox + 3.5) * 2.0 / 223.0 - 1.0,
                     (oy + 3.5) * 2.0 / 223.0 - 1.0,
                     (oz + 7.5) * 2.0 / 223.0 - 1.0 };
    for (int k = 0; k < 3; ++k)
        q[k] = ((double)M.m[3*k] * cb[0] + (double)M.m[3*k+1] * cb[1]
              + (double)M.m[3*k+2] * cb[2]) * 111.5 + 111.5;
}

extern "C" void kernel_launch(void* const* d_in, const int* in_sizes, int n_in,
                              void* d_out, int out_size, void* d_ws, size_t ws_size,
                              hipStream_t stream) {
    const float* d = (const float*)d_in[0];
    float* out = (float*)d_out;

    const double dirs[2][3] = { {2.0, 1.0, 1.0}, {-1.0, 0.5, 0.0} };
    F3 c0 = { 1.0f, 69.0f / 255.0f, 25.0f / 255.0f };
    F3 c1 = { 227.0f / 255.0f, 1.0f, 66.0f / 255.0f };
    Mat3 R[2], RT[2];
    light_mats(dirs[0], R[0], RT[0]);
    light_mats(dirs[1], R[1], RT[1]);
    F3 H8[2]  = { half_span8(R[0]),  half_span8(R[1])  };    // Run-table accept8
    F3 H16[2] = { half_span16(R[0]), half_span16(R[1]) };    // k_rot box + accept16
    F3 HB[2]  = { half_span16(RT[0]), half_span16(RT[1]) };  // k_back box

    // back-staging boxes provably interior? (mirrors device lox&~1 + x:22)
    bool bint = true;
    for (int l = 0; l < 2 && bint; ++l) {
        double H[3] = { HB[l].x, HB[l].y, HB[l].z };
        int dim[3] = { BBX, BBY, BBZ };
        for (int tz = 0; tz < NBZ16 && bint; ++tz)
            for (int ty = 0; ty < NT3 && bint; ++ty)
                for (int tx = 0; tx < NT3; ++tx) {
                    double q[3]; h_qc16(RT[l], tx * 8 + PAD, ty * 8 + PAD, tz * 16 + PAD, q);
                    for (int k = 0; k < 3; ++k) {
                        int lo = (int)floor(q[k] - H[k]);
                        if (k == 0) lo &= ~1;
                        if (lo < 1 || lo + dim[k] > LL - 1) { bint = false; break; }
                    }
                    if (!bint) break;
                }
    }

    // host-computed grid size for the compacted k_rot (double + margin ->
    // guaranteed superset of the device float accept; list itself is built
    // ON DEVICE by k_list, no H2D copy).
    static int cnt8 = -1;
    if (cnt8 < 0) {
        int cnt = 0;
        for (int l = 0; l < 2; ++l) {
            double Hx = H16[l].x + 0.01, Hy = H16[l].y + 0.01, Hz = H16[l].z + 0.01;
            for (int tz = 0; tz < NTZ16; ++tz)
                for (int ty = 0; ty < 28; ++ty)
                    for (int tx = 0; tx < 28; ++tx) {
                        double q[3];
                        h_qc16(R[l], tx * 8, ty * 8, tz * 16, q);
                        bool acc = !(q[0] + Hx < BLO || q[0] - Hx > BHI ||
                                     q[1] + Hy < BLO || q[1] - Hy > BHI ||
                                     q[2] + Hz < BLO || q[2] - Hz > BHI);
                        if (acc) ++cnt;
                    }
        }
        cnt8 = (cnt + 7) & ~7;
    }
    const int cpx = cnt8 / 8;

    // layout: f32 blocks (S0, S1, Dseg, A0, A1, List; padded), then halves
    // (W [padded], T0, T1 — 16B-aligned), then Run
    const size_t f32n = (size_t)(2 * NTZ * LL2 + NSEG * SS2 + 2 * SS2) + ROTG + 8;
    const size_t f32p = (f32n + 3) & ~(size_t)3;          // 16B-align W
    const size_t ss3p = ((size_t)SS3 + 7) & ~(size_t)7;   // 16B-align T0
    const size_t need_A = f32p * 4 + (ss3p + 2 * LL3) * 2 + 2 * 784 * 2; // ~62 MB
    const size_t need_C = (size_t)(LL3 + 3 * SS2) * 4;                   // ~45 MB

    if (ws_size >= need_A) {
        float* S0   = (float*)d_ws;
        float* S1   = S0 + NTZ * LL2;
        float* Dseg = S1 + NTZ * LL2;
        float* A0   = Dseg + NSEG * SS2;
        float* A1   = A0 + SS2;
        int*   Lst  = (int*)(A1 + SS2);
        __half* W   = (__half*)((float*)d_ws + f32p);
        __half* T0  = W + ss3p;
        __half* T1  = T0 + LL3;
        unsigned short* Run = (unsigned short*)(T1 + LL3);

        k_list <<<1, 512, 0, stream>>>(Lst, cnt8, R[0], R[1], H16[0], H16[1]);
        k_rot  <<<EXB + cnt8, 512, 0, stream>>>(d, T0, T1, S0, S1, Dseg, A0,
                                                Run, Lst, cpx,
                                                R[0], R[1], H16[0], H16[1],
                                                H8[0], H8[1]);
        k_mid  <<<MIDG, 256, 0, stream>>>(T0, T1, S0, S1, Run, d, Dseg, W);
        if (bint)
            k_back<true><<<BACKG_P, 512, 0, stream>>>(T0, T1, W, A0, A1,
                                                      RT[0], RT[1], HB[0], HB[1]);
        else
            k_back<false><<<BACKG_P, 512, 0, stream>>>(T0, T1, W, A0, A1,
                                                       RT[0], RT[1], HB[0], HB[1]);
        k_combine<<<(3 * SS2 + 255) / 256, 256, 0, stream>>>(A0, A1, out, c0, c1);
    } else if (ws_size >= need_C) {
        float* T  = (float*)d_ws;
        float* LA = T + LL3;
        for (int l = 0; l < 2; ++l) {
            k_rot_full <<<(LL3 + 255) / 256, 256, 0, stream>>>(d, T, R[l]);
            k_scan_full<<<(LL2 + 255) / 256, 256, 0, stream>>>(T);
            k_fused_back<<<(SS2 + 63) / 64, 64, 0, stream>>>(T, d, LA, RT[l],
                l ? c1.x : c0.x, l ? c1.y : c0.y, l ? c1.z : c0.z, l == 0);
        }
        k_clip<<<(3 * SS2 + 255) / 256, 256, 0, stream>>>(LA, out);
    }
}

// Round 18
// 148.493 us; speedup vs baseline: 1.2946x; 1.1345x over previous
//
#include <hip/hip_runtime.h>
#include <hip/hip_fp16.h>
#include <math.h>

#ifndef M_PI
#define M_PI 3.14159265358979323846
#endif

#define SS   129
#define LL   224
#define LL2  (LL*LL)
#define LLQ  (LL2/4)
#define LL3  (LL*LL*LL)
#define SS2  (SS*SS)
#define SS3  (SS*SS*SS)
#define CABS 0.2f
#define PAD  48

#define BLO 45.5f
#define BHI 178.5f

#define NT1  28                  // 8-tile grid per axis (Run granularity)
#define NTZ16 14                 // 16-deep rot super-tiles along z
#define ROTG  (2 * NTZ16 * 784)  // 21952 rot super-tiles = 8*7*392
#define ROTCH 392                // k_rot swizzle chunk (half z-slab)
#define NT3  17
#define NBZ16 9                  // 16-deep back super-tiles
#define BACKG (2 * NBZ16 * 289)  // 5202 logical back blocks
#define BACKCH 17                // k_back swizzle chunk
#define BACKG_P 5304             // padded: 8*39*17
#define NTZ  28

// view-ray segmentation: 16 segs of 9
#define NSEG 16
#define SEGZ 9
#define DSEGT (NSEG * SS2)                 // 266256
// k_rot pre-work blocks, dispatched FIRST:
#define EXB1 ((DSEGT + 511) / 512)         // 521: Dseg sums + A zero
#define EXB2 4                             // Run-table build
#define EXB  (EXB1 + EXB2)
#define ROTG_E (ROTG + EXB)
// k_mid: 2744 texp blocks (one thread per tile-colQUAD) + 1041 W blocks
#define TXB4 (2 * NTZ * LLQ / 256)         // 2744 exact
#define PREB1 ((DSEGT + 255) / 256)        // 1041
#define MIDG (TXB4 + PREB1)

// k_rot staging box: [y:16][z:18][x:22] (x stride 1, z stride 22, y stride 396)
// lox even-aligned for float2 staging. 396 staging threads = 2 per
// (z-row, float2-slot), each covering 8 of the 16 y-rows.
#define RBX 22
#define RBY 16
#define RBZ 18
#define RBXZ (RBX*RBZ)           // 396
#define RBN (RBX*RBY*RBZ)        // 6336 words
#define RSXH 11                  // float2 slots per row

// k_back staging box: [y:16][z:19][x:22] (x stride 1, z stride 22, y stride 418)
// lox even-aligned for half2 staging. 418 staging threads = 2 per
// (z-row, half2-slot), each covering 8 of the 16 y-rows.
#define BBX 22
#define BBY 16
#define BBZ 19
#define BBXZ (BBX*BBZ)           // 418
#define BBN (BBX*BBY*BBZ)        // 6688 words
#define BSXH 11                  // half2 slots per row

struct Mat3 { float m[9]; };
struct F3   { float x, y, z; };

__device__ __forceinline__ F3 tile_center(const Mat3& M, int ox, int oy, int oz) {
    float cbx = fmaf((float)ox + 3.5f, 2.0f / 223.0f, -1.0f);
    float cby = fmaf((float)oy + 3.5f, 2.0f / 223.0f, -1.0f);
    float cbz = fmaf((float)oz + 3.5f, 2.0f / 223.0f, -1.0f);
    F3 qc;
    qc.x = fmaf(fmaf(M.m[0], cbx, fmaf(M.m[1], cby, M.m[2] * cbz)), 111.5f, 111.5f);
    qc.y = fmaf(fmaf(M.m[3], cbx, fmaf(M.m[4], cby, M.m[5] * cbz)), 111.5f, 111.5f);
    qc.z = fmaf(fmaf(M.m[6], cbx, fmaf(M.m[7], cby, M.m[8] * cbz)), 111.5f, 111.5f);
    return qc;
}

__device__ __forceinline__ F3 tile_center16(const Mat3& M, int ox, int oy, int oz) {
    float cbx = fmaf((float)ox + 3.5f, 2.0f / 223.0f, -1.0f);
    float cby = fmaf((float)oy + 3.5f, 2.0f / 223.0f, -1.0f);
    float cbz = fmaf((float)oz + 7.5f, 2.0f / 223.0f, -1.0f);
    F3 qc;
    qc.x = fmaf(fmaf(M.m[0], cbx, fmaf(M.m[1], cby, M.m[2] * cbz)), 111.5f, 111.5f);
    qc.y = fmaf(fmaf(M.m[3], cbx, fmaf(M.m[4], cby, M.m[5] * cbz)), 111.5f, 111.5f);
    qc.z = fmaf(fmaf(M.m[6], cbx, fmaf(M.m[7], cby, M.m[8] * cbz)), 111.5f, 111.5f);
    return qc;
}

__device__ __forceinline__ bool tile_accept(F3 qc, F3 H) {
    return !(qc.x + H.x < BLO || qc.x - H.x > BHI ||
             qc.y + H.y < BLO || qc.y - H.y > BHI ||
             qc.z + H.z < BLO || qc.z - H.z > BHI);
}

__device__ __forceinline__ void qmap(const Mat3& M, int x, int y, int z,
                                     float& qx, float& qy, float& qz) {
    float bx = fmaf((float)x, 2.0f / 223.0f, -1.0f);
    float by = fmaf((float)y, 2.0f / 223.0f, -1.0f);
    float bz = fmaf((float)z, 2.0f / 223.0f, -1.0f);
    qx = fmaf(fmaf(M.m[0], bx, fmaf(M.m[1], by, M.m[2] * bz)), 111.5f, 111.5f);
    qy = fmaf(fmaf(M.m[3], bx, fmaf(M.m[4], by, M.m[5] * bz)), 111.5f, 111.5f);
    qz = fmaf(fmaf(M.m[6], bx, fmaf(M.m[7], by, M.m[8] * bz)), 111.5f, 111.5f);
}

__device__ __forceinline__ float fetch_d(const float* __restrict__ d, int z, int y, int x) {
    unsigned zz = (unsigned)(z - PAD), yy = (unsigned)(y - PAD), xx = (unsigned)(x - PAD);
    return (zz < (unsigned)SS && yy < (unsigned)SS && xx < (unsigned)SS)
        ? d[((int)zz * SS + (int)yy) * SS + (int)xx] : 0.0f;
}

__device__ __forceinline__ float fetch_T(const float* __restrict__ T, int z, int y, int x) {
    unsigned zz = (unsigned)z, yy = (unsigned)y, xx = (unsigned)x;
    return (zz < (unsigned)LL && yy < (unsigned)LL && xx < (unsigned)LL)
        ? T[((int)zz * LL + (int)yy) * LL + (int)xx] : 0.0f;
}

__device__ __forceinline__ float tri_T(const float* __restrict__ T, float qz, float qy, float qx) {
    int x0 = (int)floorf(qx), y0 = (int)floorf(qy), z0 = (int)floorf(qz);
    float wx = qx - (float)x0, wy = qy - (float)y0, wz = qz - (float)z0;
    float c000 = fetch_T(T, z0, y0, x0),     c001 = fetch_T(T, z0, y0, x0 + 1);
    float c010 = fetch_T(T, z0, y0 + 1, x0), c011 = fetch_T(T, z0, y0 + 1, x0 + 1);
    float c100 = fetch_T(T, z0 + 1, y0, x0),     c101 = fetch_T(T, z0 + 1, y0, x0 + 1);
    float c110 = fetch_T(T, z0 + 1, y0 + 1, x0), c111 = fetch_T(T, z0 + 1, y0 + 1, x0 + 1);
    float a00 = c000 + wx * (c001 - c000), a01 = c010 + wx * (c011 - c010);
    float a10 = c100 + wx * (c101 - c100), a11 = c110 + wx * (c111 - c110);
    float b0 = a00 + wy * (a01 - a00), b1 = a10 + wy * (a11 - a10);
    return b0 + wz * (b1 - b0);
}

__device__ __forceinline__ float tri_d_g(const float* __restrict__ d, float qz, float qy, float qx) {
    int x0 = (int)floorf(qx), y0 = (int)floorf(qy), z0 = (int)floorf(qz);
    float wx = qx - (float)x0, wy = qy - (float)y0, wz = qz - (float)z0;
    float c000 = fetch_d(d, z0, y0, x0),     c001 = fetch_d(d, z0, y0, x0 + 1);
    float c010 = fetch_d(d, z0, y0 + 1, x0), c011 = fetch_d(d, z0, y0 + 1, x0 + 1);
    float c100 = fetch_d(d, z0 + 1, y0, x0),     c101 = fetch_d(d, z0 + 1, y0, x0 + 1);
    float c110 = fetch_d(d, z0 + 1, y0 + 1, x0), c111 = fetch_d(d, z0 + 1, y0 + 1, x0 + 1);
    float a00 = c000 + wx * (c001 - c000), a01 = c010 + wx * (c011 - c010);
    float a10 = c100 + wx * (c101 - c100), a11 = c110 + wx * (c111 - c110);
    float b0 = a00 + wy * (a01 - a00), b1 = a10 + wy * (a11 - a10);
    return b0 + wz * (b1 - b0);
}

// trilinear from k_rot's [y:16][z:18][x:22] box (strides 396 / 22 / 1)
__device__ __forceinline__ float tri_rot(const float* __restrict__ S,
                                         float qx, float qy, float qz,
                                         int lox, int loy, int loz) {
    int x0 = (int)floorf(qx), y0 = (int)floorf(qy), z0 = (int)floorf(qz);
    float wx = qx - (float)x0, wy = qy - (float)y0, wz = qz - (float)z0;
    int i = (y0 - loy) * RBXZ + (z0 - loz) * RBX + (x0 - lox);
    float c000 = S[i],         c001 = S[i + 1];
    float cz0  = S[i + 22],    cz1  = S[i + 23];
    float cy0  = S[i + 396],   cy1  = S[i + 397];
    float cw0  = S[i + 418],   cw1  = S[i + 419];
    float a00 = c000 + wx * (c001 - c000);
    float a01 = cy0  + wx * (cy1  - cy0);
    float a10 = cz0  + wx * (cz1  - cz0);
    float a11 = cw0  + wx * (cw1  - cw0);
    float b0  = a00 + wy * (a01 - a00);
    float b1  = a10 + wy * (a11 - a10);
    return b0 + wz * (b1 - b0);
}

// trilinear from k_back's [y:16][z:19][x:22] box (strides 418 / 22 / 1)
__device__ __forceinline__ float tri_back(const float* __restrict__ S,
                                          float qx, float qy, float qz,
                                          int lox, int loy, int loz) {
    int x0 = (int)floorf(qx), y0 = (int)floorf(qy), z0 = (int)floorf(qz);
    float wx = qx - (float)x0, wy = qy - (float)y0, wz = qz - (float)z0;
    int i = (y0 - loy) * BBXZ + (z0 - loz) * BBX + (x0 - lox);
    float c000 = S[i],         c001 = S[i + 1];
    float cz0  = S[i + 22],    cz1  = S[i + 23];
    float cy0  = S[i + 418],   cy1  = S[i + 419];
    float cw0  = S[i + 440],   cw1  = S[i + 441];
    float a00 = c000 + wx * (c001 - c000);
    float a01 = cy0  + wx * (cy1  - cy0);
    float a10 = cz0  + wx * (cz1  - cz0);
    float a11 = cw0  + wx * (cw1  - cw0);
    float b0  = a00 + wy * (a01 - a00);
    float b1  = a10 + wy * (a11 - a10);
    return b0 + wz * (b1 - b0);
}

// K1: pre-work blocks FIRST [0,EXB): Dseg sums + A zero + Run table.
// Rot blocks [EXB, ROTG_E): swizzled 8x8x16 super-tiles, inline bbox
// self-accept, float2 staging (396 threads = 2 per (z,slot), 8 y-rows each;
// lox even), raw-sample packed T store + per-tile Ssum totals.
__global__ __launch_bounds__(512) void k_rot(const float* __restrict__ d,
        __half* __restrict__ T0, __half* __restrict__ T1,
        float* __restrict__ S0, float* __restrict__ S1,
        float* __restrict__ Dseg, float* __restrict__ A,
        unsigned short* __restrict__ Run,
        Mat3 M0, Mat3 M1, F3 H0, F3 H1, F3 G0, F3 G1) {
    int n = blockIdx.x;
    int tid = threadIdx.x;
    if (n < EXB) {                          // ---- pre-work ----
        if (n < EXB1) {
            int t = n * 512 + tid;
            if (t < 2 * SS2) A[t] = 0.0f;
            if (t >= DSEGT) return;
            int seg = t / SS2, col = t - seg * SS2;
            int zs = seg * SEGZ, ze = min(SS, zs + SEGZ);
            float run = 0.0f;
            for (int z = zs; z < ze; ++z) run += d[z * SS2 + col];
            Dseg[t] = run;
        } else {
            int id = (n - EXB1) * 512 + tid;
            if (id >= 2 * 784) return;
            int l = id / 784, r = id - l * 784;
            int ty = r / 28, tx = r - ty * 28;
            const Mat3 M = l ? M1 : M0;
            const F3  G  = l ? G1 : G0;
            int t0 = -1, t1 = -1;
            for (int tz = 0; tz < NT1; ++tz) {
                F3 qc = tile_center(M, tx * 8, ty * 8, tz * 8);
                if (tile_accept(qc, G)) { if (t0 < 0) t0 = tz; t1 = tz; }
            }
            Run[id] = (t0 < 0) ? 0xFFFFu : (unsigned short)(t0 | (t1 << 8));
        }
        return;
    }

    int nn = n - EXB;
    int x8 = nn & 7, i8 = nn >> 3;          // XCD, index-within-XCD
    int c = i8 / ROTCH, off = i8 - c * ROTCH;
    int b = (c * 8 + x8) * ROTCH + off;     // bijective logical id

    int light = b / (NTZ16 * 784);
    int r = b - light * (NTZ16 * 784);
    int tz16 = r / 784;
    int r2 = r - tz16 * 784;
    int tty = r2 / 28, ttx = r2 - tty * 28;

    const Mat3 M = light ? M1 : M0;
    const F3  H  = light ? H1 : H0;           // H16
    __half* __restrict__ T   = light ? T1 : T0;
    float* __restrict__ Ssum = light ? S1 : S0;

    int ox = ttx * 8, oy = tty * 8, oz = tz16 * 16;
    F3 qc = tile_center16(M, ox, oy, oz);
    if (!tile_accept(qc, H)) return;          // superset of Run hull (convexity)

    int lox = (int)floorf(qc.x - H.x);
    lox &= ~1;                                // even for float2 staging
    int loy = (int)floorf(qc.y - H.y);
    int loz = (int)floorf(qc.z - H.z);

    __shared__ float S[RBN];
    __shared__ float Sc[1024];

    if (tid < 2 * RSXH * RBZ) {               // 396 staging threads
        int ixh = tid % RSXH;                 // float2 slot 0..10
        int izz = tid / RSXH;                 // 0..35
        int jb = 0;
        if (izz >= RBZ) { izz -= RBZ; jb = 8; }   // second half: y-rows 8..15
        bool interior = (lox >= PAD) & (lox <= PAD + SS - RBX) &
                        (loy >= PAD) & (loy <= PAD + SS - RBY) &
                        (loz >= PAD) & (loz <= PAD + SS - RBZ);
        int si = jb * RBXZ + izz * RBX + 2 * ixh;
        if (interior) {
            const float* g = d + ((size_t)(loz + izz - PAD) * SS + (loy + jb - PAD)) * SS
                               + (lox + 2 * ixh - PAD);
            #pragma unroll
            for (int j = 0; j < 8; ++j)
                *(float2*)&S[si + j * RBXZ] = *(const float2*)&g[j * SS];
        } else {
            int gx0 = lox + 2 * ixh;
            #pragma unroll
            for (int j = 0; j < 8; ++j) {
                S[si + j * RBXZ]     = fetch_d(d, loz + izz, loy + jb + j, gx0);
                S[si + j * RBXZ + 1] = fetch_d(d, loz + izz, loy + jb + j, gx0 + 1);
            }
        }
    }
    __syncthreads();

    int lx = tid & 7, ly = (tid >> 3) & 7, lz = tid >> 6;
    int col = tid & 63;
    float fx = (float)lx - 3.5f, fy = (float)ly - 3.5f, fz = (float)lz - 7.5f;
    float qx = qc.x + fmaf(M.m[0], fx, fmaf(M.m[1], fy, M.m[2] * fz));
    float qy = qc.y + fmaf(M.m[3], fx, fmaf(M.m[4], fy, M.m[5] * fz));
    float qz = qc.z + fmaf(M.m[6], fx, fmaf(M.m[7], fy, M.m[8] * fz));
    float v0 = tri_rot(S, qx, qy, qz, lox, loy, loz);
    float qx2 = qx + 8.0f * M.m[2];
    float qy2 = qy + 8.0f * M.m[5];
    float qz2 = qz + 8.0f * M.m[8];
    float v1 = tri_rot(S, qx2, qy2, qz2, lox, loy, loz);

    Sc[lz * 64 + col] = v0;
    Sc[(lz + 8) * 64 + col] = v1;
    __syncthreads();
    // merged read-only tail: waves 0-1 pack raw T rows; waves 2-3 Ssum totals
    if (tid < 128) {
        int zz = tid >> 3, ly2 = tid & 7;
        const float4* Sc4 = (const float4*)Sc;
        float4 f0 = Sc4[zz * 16 + ly2 * 2];
        float4 f1 = Sc4[zz * 16 + ly2 * 2 + 1];
        union { __half2 h[4]; float4 v; } u;
        u.h[0] = __floats2half2_rn(f0.x, f0.y);
        u.h[1] = __floats2half2_rn(f0.z, f0.w);
        u.h[2] = __floats2half2_rn(f1.x, f1.y);
        u.h[3] = __floats2half2_rn(f1.z, f1.w);
        *(float4*)&T[(size_t)(oz + zz) * LL2 + (oy + ly2) * LL + ox] = u.v;
    } else if (tid < 256) {
        int t2 = tid - 128;
        int cc = t2 & 63, h = t2 >> 6;      // h=0: lower 8-tile, h=1: upper
        float s = 0.0f;
        #pragma unroll
        for (int k = 0; k < 8; ++k) s += Sc[(h * 8 + k) * 64 + cc];
        int so = (oy + (cc >> 3)) * LL + (ox + (cc & 7));
        Ssum[(2 * tz16 + h) * LL2 + so] = s;
    }
}

// k_mid: blocks [0,TXB4): transmittance. One thread per (light, tile,
//   column-QUAD): single Run lookup (4-aligned col stays in one 8-tile),
//   cross-tile suffix via float4 Ssum loads, T via float2 (4 halves)
//   loads/stores, in-register 8-deep suffix + exp, in place.
//   blocks [TXB4,MIDG): W write (fp16) from d + Dseg.
__global__ __launch_bounds__(256) void k_mid(__half* __restrict__ T0,
        __half* __restrict__ T1, const float* __restrict__ S0,
        const float* __restrict__ S1, const unsigned short* __restrict__ Run,
        const float* __restrict__ d, const float* __restrict__ Dseg,
        __half* __restrict__ W) {
    int b = blockIdx.x;
    if (b < TXB4) {
        int id = b * 256 + threadIdx.x;        // < 2*NTZ*LLQ exactly
        int light = id / (NTZ * LLQ);
        int r = id - light * (NTZ * LLQ);
        int t = r / LLQ, cq = r - t * LLQ;
        int col = cq * 4;
        int y = col / LL, x = col - y * LL;    // x mult of 4 -> one 8-tile
        unsigned short rt = Run[light * 784 + (y >> 3) * 28 + (x >> 3)];
        if (rt == 0xFFFFu) return;
        int t0 = rt & 0xFF, t1 = rt >> 8;
        if (t < t0 || t > t1) return;
        const float* __restrict__ Ssum = light ? S1 : S0;
        float oA = 0.0f, oB = 0.0f, oC = 0.0f, oD = 0.0f;
        for (int tp = t + 1; tp <= t1; ++tp) {
            float4 s4 = *(const float4*)&Ssum[tp * LL2 + col];  // 16B aligned
            oA += s4.x; oB += s4.y; oC += s4.z; oD += s4.w;
        }
        float2* __restrict__ Tp =
            (float2*)((__half*)(light ? T1 : T0) + (size_t)(8 * t) * LL2 + col);
        float2 raw[8];
        #pragma unroll
        for (int k = 0; k < 8; ++k) raw[k] = Tp[k * LLQ];   // 4 halves each
        float4 v[8];
        #pragma unroll
        for (int k = 0; k < 8; ++k) {
            __half2 h0 = ((__half2*)&raw[k])[0];
            __half2 h1 = ((__half2*)&raw[k])[1];
            float2 f0 = __half22float2(h0), f1 = __half22float2(h1);
            v[k] = make_float4(f0.x, f0.y, f1.x, f1.y);
        }
        float sA = oA, sB = oB, sC = oC, sD = oD;
        #pragma unroll
        for (int k = 7; k >= 0; --k) {
            sA += v[k].x; sB += v[k].y; sC += v[k].z; sD += v[k].w;
            v[k].x = sA; v[k].y = sB; v[k].z = sC; v[k].w = sD;
        }
        #pragma unroll
        for (int k = 0; k < 8; ++k) {
            __half2 h0 = __floats2half2_rn(__expf(-CABS * v[k].x),
                                           __expf(-CABS * v[k].y));
            __half2 h1 = __floats2half2_rn(__expf(-CABS * v[k].z),
                                           __expf(-CABS * v[k].w));
            float2 o;
            ((__half2*)&o)[0] = h0;
            ((__half2*)&o)[1] = h1;
            Tp[k * LLQ] = o;
        }
    } else {
        int t = (b - TXB4) * 256 + threadIdx.x;
        if (t >= DSEGT) return;
        int seg = t / SS2, col = t - seg * SS2;
        int zs = seg * SEGZ, ze = min(SS, zs + SEGZ);
        float run = 0.0f;
        for (int s2 = seg + 1; s2 < NSEG; ++s2) run += Dseg[s2 * SS2 + col];
        for (int z = ze - 1; z >= zs; --z) {
            float dv = d[z * SS2 + col];
            run += dv;
            W[z * SS2 + col] = __float2half(dv * __expf(-CABS * run));
        }
    }
}

// K3: 8x8x16 super-tile; half2 staging of transmittance (418 threads = 2 per
// (z,slot), 8 y-rows each; lox even), back-rotate, *W16, reduce.
// XCD-chunked swizzle, padded grid.
template<bool BINT>
__global__ __launch_bounds__(512) void k_back(const __half* __restrict__ T0,
        const __half* __restrict__ T1, const __half* __restrict__ W,
        float* __restrict__ A0, float* __restrict__ A1,
        Mat3 M0, Mat3 M1, F3 H0, F3 H1) {
    int n = blockIdx.x;
    int x8 = n & 7, i8 = n >> 3;
    int c = i8 / BACKCH, off = i8 - c * BACKCH;
    int lb = (c * 8 + x8) * BACKCH + off;
    if (lb >= BACKG) return;

    int light = lb / (NBZ16 * 289); lb -= light * (NBZ16 * 289);
    int tz16 = lb / 289;
    int r2 = lb - tz16 * 289;
    int tty = r2 / 17, ttx = r2 - tty * 17;

    const Mat3 M = light ? M1 : M0;
    const F3  H  = light ? H1 : H0;
    const __half* __restrict__ T = light ? T1 : T0;
    float* __restrict__ A = light ? A1 : A0;

    int ox = ttx * 8, oy = tty * 8, oz = tz16 * 16;
    F3 qc = tile_center16(M, ox + PAD, oy + PAD, oz + PAD);
    int lox = (int)floorf(qc.x - H.x);
    lox &= ~1;                                // even for half2 staging
    int loy = (int)floorf(qc.y - H.y);
    int loz = (int)floorf(qc.z - H.z);

    __shared__ float S[BBN];
    __shared__ float Sc[512];
    int tid = threadIdx.x;

    if (tid < 2 * BSXH * BBZ) {               // 418 staging threads
        int ixh = tid % BSXH;                 // half2 slot 0..10
        int izz = tid / BSXH;                 // 0..37
        int jb = 0;
        if (izz >= BBZ) { izz -= BBZ; jb = 8; }   // second half: y-rows 8..15
        int si = jb * BBXZ + izz * BBX + 2 * ixh;
        if (BINT) {
            const __half2* g = (const __half2*)
                (T + ((size_t)(loz + izz) * LL + (loy + jb)) * LL + (lox + 2 * ixh));
            #pragma unroll
            for (int j = 0; j < 8; ++j)
                *(float2*)&S[si + j * BBXZ] = __half22float2(g[j * (LL / 2)]);
        } else {
            int gx0 = lox + 2 * ixh, gx1 = gx0 + 1;
            #pragma unroll
            for (int j = 0; j < 8; ++j) {
                int gz = loz + izz, gy = loy + jb + j;
                bool zy = ((unsigned)gz < (unsigned)LL) & ((unsigned)gy < (unsigned)LL);
                size_t rowb = ((size_t)gz * LL + gy) * LL;
                S[si + j * BBXZ]     = (zy && (unsigned)gx0 < (unsigned)LL)
                                     ? __half2float(T[rowb + gx0]) : 0.0f;
                S[si + j * BBXZ + 1] = (zy && (unsigned)gx1 < (unsigned)LL)
                                     ? __half2float(T[rowb + gx1]) : 0.0f;
            }
        }
    }
    __syncthreads();

    int lx = tid & 7, ly = (tid >> 3) & 7, lz = tid >> 6;
    int col = tid & 63;
    int x = ox + lx, y = oy + ly;
    float v0 = 0.0f, v1 = 0.0f;
    if (x < SS && y < SS) {
        float fx = (float)lx - 3.5f, fy = (float)ly - 3.5f, fz = (float)lz - 7.5f;
        float qx = qc.x + fmaf(M.m[0], fx, fmaf(M.m[1], fy, M.m[2] * fz));
        float qy = qc.y + fmaf(M.m[3], fx, fmaf(M.m[4], fy, M.m[5] * fz));
        float qz = qc.z + fmaf(M.m[6], fx, fmaf(M.m[7], fy, M.m[8] * fz));
        int z0 = oz + lz, z1 = oz + 8 + lz;
        if (z0 < SS)
            v0 = tri_back(S, qx, qy, qz, lox, loy, loz)
               * __half2float(W[(z0 * SS + y) * SS + x]);
        if (z1 < SS) {
            float qx2 = qx + 8.0f * M.m[2];
            float qy2 = qy + 8.0f * M.m[5];
            float qz2 = qz + 8.0f * M.m[8];
            v1 = tri_back(S, qx2, qy2, qz2, lox, loy, loz)
               * __half2float(W[(z1 * SS + y) * SS + x]);
        }
    }
    Sc[lz * 64 + col] = v0 + v1;
    __syncthreads();
    if (tid < 64) {
        float s = 0.0f;
        #pragma unroll
        for (int k = 0; k < 8; ++k) s += Sc[k * 64 + tid];
        int xx = ox + (tid & 7), yy = oy + (tid >> 3);
        if (xx < SS && yy < SS) atomicAdd(&A[yy * SS + xx], s);
    }
}

__global__ __launch_bounds__(256) void k_combine(const float* __restrict__ A0,
        const float* __restrict__ A1, float* __restrict__ out, F3 c0, F3 c1) {
    int i = blockIdx.x * 256 + threadIdx.x;
    if (i >= 3 * SS2) return;
    int ch = i / SS2, col = i - ch * SS2;
    float r0 = (ch == 0) ? c0.x : ((ch == 1) ? c0.y : c0.z);
    float r1 = (ch == 0) ? c1.x : ((ch == 1) ? c1.y : c1.z);
    float o = CABS * (A0[col] * r0 + A1[col] * r1);
    out[i] = fminf(fmaxf(o, 0.0f), 1.0f);
}

// ---- minimal-workspace fallback ----
__global__ __launch_bounds__(256) void k_rot_full(const float* __restrict__ d,
                                                  float* __restrict__ T, Mat3 R) {
    int i = blockIdx.x * 256 + threadIdx.x;
    if (i >= LL3) return;
    int x = i % LL; int r = i / LL; int y = r % LL; int z = r / LL;
    float qx, qy, qz; qmap(R, x, y, z, qx, qy, qz);
    T[i] = tri_d_g(d, qz, qy, qx);
}

__global__ __launch_bounds__(256) void k_scan_full(float* __restrict__ T) {
    int col = blockIdx.x * 256 + threadIdx.x;
    if (col >= LL2) return;
    float run = 0.0f;
    for (int z = LL - 1; z >= 0; --z) {
        int idx = z * LL2 + col;
        run += T[idx];
        T[idx] = __expf(-CABS * run);
    }
}

__global__ __launch_bounds__(64) void k_fused_back(const float* __restrict__ T,
        const float* __restrict__ d, float* __restrict__ LA, Mat3 RT,
        float cr, float cg, float cb, int first) {
    int col = blockIdx.x * 64 + threadIdx.x;
    if (col >= SS2) return;
    int y = col / SS, x = col % SS;
    float run = 0.0f, acc = 0.0f;
    for (int z = SS - 1; z >= 0; --z) {
        float qx, qy, qz; qmap(RT, x + PAD, y + PAD, z + PAD, qx, qy, qz);
        float u = tri_T(T, qz, qy, qx);
        float dv = d[z * SS2 + col];
        run += dv;
        acc = fmaf(dv * __expf(-CABS * run), u, acc);
    }
    if (first) {
        LA[0 * SS2 + col] = acc * cr;
        LA[1 * SS2 + col] = acc * cg;
        LA[2 * SS2 + col] = acc * cb;
    } else {
        LA[0 * SS2 + col] += acc * cr;
        LA[1 * SS2 + col] += acc * cg;
        LA[2 * SS2 + col] += acc * cb;
    }
}

__global__ __launch_bounds__(256) void k_clip(const float* __restrict__ LA,
                                              float* __restrict__ out) {
    int i = blockIdx.x * 256 + threadIdx.x;
    if (i < 3 * SS2) out[i] = fminf(fmaxf(CABS * LA[i], 0.0f), 1.0f);
}

static void light_mats(const double ld_in[3], Mat3& R, Mat3& RT) {
    double n = sqrt(ld_in[0]*ld_in[0] + ld_in[1]*ld_in[1] + ld_in[2]*ld_in[2]);
    double l0 = ld_in[0]/n, l1 = ld_in[1]/n, l2 = ld_in[2]/n;
    double yv = -asin(l0);
    if (l2 < 0) yv = -M_PI - yv;
    double yd = yv * 180.0 / M_PI, pd = asin(l1) * 180.0 / M_PI;
    double yr = yd * M_PI / 180.0, pr = pd * M_PI / 180.0;
    float cy = (float)cos(yr), sy = (float)sin(yr), cp = (float)cos(pr), sp = (float)sin(pr);
    float m[9] = { cy,  sy*sp,  sy*cp,
                   0.f, cp,    -sp,
                  -sy,  cy*sp,  cy*cp };
    for (int i = 0; i < 9; ++i) R.m[i] = m[i];
    RT.m[0] = m[0]; RT.m[1] = m[3]; RT.m[2] = m[6];
    RT.m[3] = m[1]; RT.m[4] = m[4]; RT.m[5] = m[7];
    RT.m[6] = m[2]; RT.m[7] = m[5]; RT.m[8] = m[8];
}

static F3 half_span8(const Mat3& M) {
    F3 h;
    h.x = 3.5f * (fabsf(M.m[0]) + fabsf(M.m[1]) + fabsf(M.m[2])) + 0.05f;
    h.y = 3.5f * (fabsf(M.m[3]) + fabsf(M.m[4]) + fabsf(M.m[5])) + 0.05f;
    h.z = 3.5f * (fabsf(M.m[6]) + fabsf(M.m[7]) + fabsf(M.m[8])) + 0.05f;
    return h;
}

static F3 half_span16(const Mat3& M) {
    F3 h;
    h.x = 3.5f * (fabsf(M.m[0]) + fabsf(M.m[1])) + 7.5f * fabsf(M.m[2]) + 0.1f;
    h.y = 3.5f * (fabsf(M.m[3]) + fabsf(M.m[4])) + 7.5f * fabsf(M.m[5]) + 0.1f;
    h.z = 3.5f * (fabsf(M.m[6]) + fabsf(M.m[7])) + 7.5f * fabsf(M.m[8]) + 0.1f;
    return h;
}

static void h_qc16(const Mat3& M, double ox, double oy, double oz, double q[3]) {
    double cb[3] = { (ox + 3.5) * 2.0 / 223.0 - 1.0,
                     (oy + 3.5) * 2.0 / 223.0 - 1.0,
                     (oz + 7.5) * 2.0 / 223.0 - 1.0 };
    for (int k = 0; k < 3; ++k)
        q[k] = ((double)M.m[3*k] * cb[0] + (double)M.m[3*k+1] * cb[1]
              + (double)M.m[3*k+2] * cb[2]) * 111.5 + 111.5;
}

extern "C" void kernel_launch(void* const* d_in, const int* in_sizes, int n_in,
                              void* d_out, int out_size, void* d_ws, size_t ws_size,
                              hipStream_t stream) {
    const float* d = (const float*)d_in[0];
    float* out = (float*)d_out;

    const double dirs[2][3] = { {2.0, 1.0, 1.0}, {-1.0, 0.5, 0.0} };
    F3 c0 = { 1.0f, 69.0f / 255.0f, 25.0f / 255.0f };
    F3 c1 = { 227.0f / 255.0f, 1.0f, 66.0f / 255.0f };
    Mat3 R[2], RT[2];
    light_mats(dirs[0], R[0], RT[0]);
    light_mats(dirs[1], R[1], RT[1]);
    F3 H8[2]  = { half_span8(R[0]),  half_span8(R[1])  };    // Run-table accept8
    F3 H16[2] = { half_span16(R[0]), half_span16(R[1]) };    // k_rot box + accept16
    F3 HB[2]  = { half_span16(RT[0]), half_span16(RT[1]) };  // k_back box

    // back-staging boxes provably interior? (mirrors device lox&~1 + x:22)
    bool bint = true;
    for (int l = 0; l < 2 && bint; ++l) {
        double H[3] = { HB[l].x, HB[l].y, HB[l].z };
        int dim[3] = { BBX, BBY, BBZ };
        for (int tz = 0; tz < NBZ16 && bint; ++tz)
            for (int ty = 0; ty < NT3 && bint; ++ty)
                for (int tx = 0; tx < NT3; ++tx) {
                    double q[3]; h_qc16(RT[l], tx * 8 + PAD, ty * 8 + PAD, tz * 16 + PAD, q);
                    for (int k = 0; k < 3; ++k) {
                        int lo = (int)floor(q[k] - H[k]);
                        if (k == 0) lo &= ~1;
                        if (lo < 1 || lo + dim[k] > LL - 1) { bint = false; break; }
                    }
                    if (!bint) break;
                }
    }

    // layout: f32 blocks (S0, S1, Dseg, A0, A1; padded to 16B), then halves
    // (W [padded], T0, T1 — 16B-aligned), then Run
    const size_t f32n = (size_t)(2 * NTZ * LL2 + NSEG * SS2 + 2 * SS2);
    const size_t f32p = (f32n + 3) & ~(size_t)3;          // 16B-align W
    const size_t ss3p = ((size_t)SS3 + 7) & ~(size_t)7;   // 16B-align T0
    const size_t need_A = f32p * 4 + (ss3p + 2 * LL3) * 2 + 2 * 784 * 2; // ~62 MB
    const size_t need_C = (size_t)(LL3 + 3 * SS2) * 4;                   // ~45 MB

    if (ws_size >= need_A) {
        float* S0   = (float*)d_ws;
        float* S1   = S0 + NTZ * LL2;
        float* Dseg = S1 + NTZ * LL2;
        float* A0   = Dseg + NSEG * SS2;
        float* A1   = A0 + SS2;
        __half* W   = (__half*)((float*)d_ws + f32p);
        __half* T0  = W + ss3p;
        __half* T1  = T0 + LL3;
        unsigned short* Run = (unsigned short*)(T1 + LL3);

        k_rot  <<<ROTG_E, 512, 0, stream>>>(d, T0, T1, S0, S1, Dseg, A0, Run,
                                            R[0], R[1], H16[0], H16[1], H8[0], H8[1]);
        k_mid  <<<MIDG, 256, 0, stream>>>(T0, T1, S0, S1, Run, d, Dseg, W);
        if (bint)
            k_back<true><<<BACKG_P, 512, 0, stream>>>(T0, T1, W, A0, A1,
                                                      RT[0], RT[1], HB[0], HB[1]);
        else
            k_back<false><<<BACKG_P, 512, 0, stream>>>(T0, T1, W, A0, A1,
                                                       RT[0], RT[1], HB[0], HB[1]);
        k_combine<<<(3 * SS2 + 255) / 256, 256, 0, stream>>>(A0, A1, out, c0, c1);
    } else if (ws_size >= need_C) {
        float* T  = (float*)d_ws;
        float* LA = T + LL3;
        for (int l = 0; l < 2; ++l) {
            k_rot_full <<<(LL3 + 255) / 256, 256, 0, stream>>>(d, T, R[l]);
            k_scan_full<<<(LL2 + 255) / 256, 256, 0, stream>>>(T);
            k_fused_back<<<(SS2 + 63) / 64, 64, 0, stream>>>(T, d, LA, RT[l],
                l ? c1.x : c0.x, l ? c1.y : c0.y, l ? c1.z : c0.z, l == 0);
        }
        k_clip<<<(3 * SS2 + 255) / 256, 256, 0, stream>>>(LA, out);
    }
}